// Round 2
// baseline (2192.005 us; speedup 1.0000x reference)
//
#include <hip/hip_runtime.h>
#include <hip/hip_bf16.h>

#define N_NODES 50000
#define N_EDGES 400000
#define N_REL   3
#define NEG_SLOPE 0.2f

// ---------------- CSR build ----------------

__global__ void count_kernel(const int* __restrict__ dst, int* __restrict__ cnt, int total) {
  int i = blockIdx.x * 256 + threadIdx.x;
  if (i < total) {
    int r = i / N_EDGES;
    atomicAdd(&cnt[r * N_NODES + dst[i]], 1);
  }
}

__global__ void scan_kernel(const int* __restrict__ cnt, int* __restrict__ row_ptr,
                            int* __restrict__ cursor) {
  __shared__ int tmp[1024];
  int r = blockIdx.x;
  int t = threadIdx.x;
  const int chunk = (N_NODES + 1023) / 1024;  // 49
  int base = t * chunk;
  int s = 0;
  for (int j = 0; j < chunk; j++) {
    int i = base + j;
    if (i < N_NODES) s += cnt[r * N_NODES + i];
  }
  tmp[t] = s;
  __syncthreads();
  for (int off = 1; off < 1024; off <<= 1) {
    int v = (t >= off) ? tmp[t - off] : 0;
    __syncthreads();
    tmp[t] += v;
    __syncthreads();
  }
  int run = tmp[t] - s;  // exclusive prefix
  for (int j = 0; j < chunk; j++) {
    int i = base + j;
    if (i < N_NODES) {
      row_ptr[r * (N_NODES + 1) + i] = run;
      cursor[r * N_NODES + i] = run;
      run += cnt[r * N_NODES + i];
    }
  }
  if (t == 0) row_ptr[r * (N_NODES + 1) + N_NODES] = tmp[1023];
}

__global__ void scatter_kernel(const int* __restrict__ src, const int* __restrict__ dst,
                               int* __restrict__ cursor, int* __restrict__ col, int total) {
  int i = blockIdx.x * 256 + threadIdx.x;
  if (i < total) {
    int r = i / N_EDGES;
    int d = dst[i];
    int pos = atomicAdd(&cursor[r * N_NODES + d], 1);
    col[r * N_EDGES + pos] = src[i];
  }
}

// ---------------- GEMM: feat(M,256) = A(M,256) * W(256,256), all fp32 ----------------
// fp32 VALU, tiled 128x128, BK=32, 256 threads, 8x8 per thread.

__global__ __launch_bounds__(256, 2) void gemm_kernel(const float* __restrict__ A,
                                                      const float* __restrict__ Bw,
                                                      float* __restrict__ C, int M) {
  const int BM = 128, BK = 32, LDA = BM + 4, LDB = 128 + 4;
  __shared__ float As[BK * LDA];  // As[k][m]
  __shared__ float Bs[BK * LDB];  // Bs[k][n]
  const int tid = threadIdx.x;
  const int m0 = blockIdx.x * BM, n0 = blockIdx.y * 128;
  const int tx = tid & 15;   // 16 col groups: cols tx*4..+3 and 64+tx*4..+3
  const int ty = tid >> 4;   // 16 row groups: rows ty*8..+7

  float acc[8][8];
#pragma unroll
  for (int i = 0; i < 8; i++)
#pragma unroll
    for (int j = 0; j < 8; j++) acc[i][j] = 0.0f;

  for (int kb = 0; kb < 8; kb++) {
    int k0 = kb * 32;
    // A tile: 128 rows x 32 k = 1024 float4
#pragma unroll
    for (int j = 0; j < 4; j++) {
      int f = tid + 256 * j;
      int rr = f >> 3;            // 0..127
      int kk = (f & 7) << 2;      // 0,4,...,28
      int gm = m0 + rr;
      float4 v = make_float4(0.f, 0.f, 0.f, 0.f);
      if (gm < M) v = *(const float4*)&A[gm * 256 + k0 + kk];
      As[(kk + 0) * LDA + rr] = v.x;
      As[(kk + 1) * LDA + rr] = v.y;
      As[(kk + 2) * LDA + rr] = v.z;
      As[(kk + 3) * LDA + rr] = v.w;
    }
    // B tile: 32 k-rows x 128 cols (fp32)
#pragma unroll
    for (int j = 0; j < 4; j++) {
      int f = tid + 256 * j;      // float4 index, 32 per row
      int kr = f >> 5;            // 0..31
      int c = (f & 31) << 2;      // 0..124
      float4 w = *(const float4*)&Bw[(k0 + kr) * 256 + n0 + c];
      Bs[kr * LDB + c + 0] = w.x;
      Bs[kr * LDB + c + 1] = w.y;
      Bs[kr * LDB + c + 2] = w.z;
      Bs[kr * LDB + c + 3] = w.w;
    }
    __syncthreads();
#pragma unroll
    for (int k = 0; k < 32; k++) {
      float4 a0 = *(const float4*)&As[k * LDA + ty * 8];
      float4 a1 = *(const float4*)&As[k * LDA + ty * 8 + 4];
      float4 b0 = *(const float4*)&Bs[k * LDB + tx * 4];
      float4 b1 = *(const float4*)&Bs[k * LDB + 64 + tx * 4];
      float av[8] = {a0.x, a0.y, a0.z, a0.w, a1.x, a1.y, a1.z, a1.w};
      float bv[8] = {b0.x, b0.y, b0.z, b0.w, b1.x, b1.y, b1.z, b1.w};
#pragma unroll
      for (int i = 0; i < 8; i++)
#pragma unroll
        for (int j = 0; j < 8; j++) acc[i][j] += av[i] * bv[j];
    }
    __syncthreads();
  }
#pragma unroll
  for (int i = 0; i < 8; i++) {
    int gm = m0 + ty * 8 + i;
    if (gm < M) {
      *(float4*)&C[gm * 256 + n0 + tx * 4] =
          make_float4(acc[i][0], acc[i][1], acc[i][2], acc[i][3]);
      *(float4*)&C[gm * 256 + n0 + 64 + tx * 4] =
          make_float4(acc[i][4], acc[i][5], acc[i][6], acc[i][7]);
    }
  }
}

// ---------------- el/er: per-node attention logits ----------------

__global__ void elr_kernel(const float* __restrict__ feat,
                           const float* __restrict__ al,
                           const float* __restrict__ ar,
                           float* __restrict__ el, float* __restrict__ er) {
  int node = blockIdx.x * 4 + (threadIdx.x >> 6);
  int lane = threadIdx.x & 63;
  if (node >= N_NODES) return;
  float e1[4], e2[4];
#pragma unroll
  for (int h = 0; h < 4; h++) {
    float v = feat[node * 256 + h * 64 + lane];
    e1[h] = v * al[h * 64 + lane];
    e2[h] = v * ar[h * 64 + lane];
  }
#pragma unroll
  for (int off = 32; off > 0; off >>= 1)
#pragma unroll
    for (int h = 0; h < 4; h++) {
      e1[h] += __shfl_down(e1[h], off);
      e2[h] += __shfl_down(e2[h], off);
    }
  if (lane == 0) {
    ((float4*)el)[node] = make_float4(e1[0], e1[1], e1[2], e1[3]);
    ((float4*)er)[node] = make_float4(e2[0], e2[1], e2[2], e2[3]);
  }
}

// ---------------- per-dst aggregation with online softmax ----------------

__global__ void agg_kernel(const float* __restrict__ feat,
                           const float* __restrict__ el, const float* __restrict__ er,
                           const int* __restrict__ row_ptr, const int* __restrict__ col,
                           const float* __restrict__ bias,
                           float* __restrict__ hout, int accum) {
  int n = blockIdx.x * 4 + (threadIdx.x >> 6);
  int lane = threadIdx.x & 63;
  if (n >= N_NODES) return;
  float4 ern = ((const float4*)er)[n];
  int s0 = row_ptr[n], s1 = row_ptr[n + 1];
  float m0 = -1e30f, m1 = -1e30f, m2 = -1e30f, m3 = -1e30f;
  float l0 = 0.f, l1 = 0.f, l2 = 0.f, l3 = 0.f;
  float a0 = 0.f, a1 = 0.f, a2 = 0.f, a3 = 0.f;
  for (int i = s0; i < s1; i++) {
    int s = col[i];
    float4 els = ((const float4*)el)[s];
    float e0 = els.x + ern.x; e0 = e0 > 0.f ? e0 : NEG_SLOPE * e0;
    float e1 = els.y + ern.y; e1 = e1 > 0.f ? e1 : NEG_SLOPE * e1;
    float e2 = els.z + ern.z; e2 = e2 > 0.f ? e2 : NEG_SLOPE * e2;
    float e3 = els.w + ern.w; e3 = e3 > 0.f ? e3 : NEG_SLOPE * e3;
    const float* fs = feat + s * 256 + lane;
    float f0 = fs[0], f1 = fs[64], f2 = fs[128], f3 = fs[192];
    float nm;
    nm = fmaxf(m0, e0); { float sc = __expf(m0 - nm), p = __expf(e0 - nm);
      a0 = a0 * sc + p * f0; l0 = l0 * sc + p; m0 = nm; }
    nm = fmaxf(m1, e1); { float sc = __expf(m1 - nm), p = __expf(e1 - nm);
      a1 = a1 * sc + p * f1; l1 = l1 * sc + p; m1 = nm; }
    nm = fmaxf(m2, e2); { float sc = __expf(m2 - nm), p = __expf(e2 - nm);
      a2 = a2 * sc + p * f2; l2 = l2 * sc + p; m2 = nm; }
    nm = fmaxf(m3, e3); { float sc = __expf(m3 - nm), p = __expf(e3 - nm);
      a3 = a3 * sc + p * f3; l3 = l3 * sc + p; m3 = nm; }
  }
  float o0 = a0 / fmaxf(l0, 1e-9f) + bias[0 * 64 + lane];
  float o1 = a1 / fmaxf(l1, 1e-9f) + bias[1 * 64 + lane];
  float o2 = a2 / fmaxf(l2, 1e-9f) + bias[2 * 64 + lane];
  float o3 = a3 / fmaxf(l3, 1e-9f) + bias[3 * 64 + lane];
  o0 = o0 > 0.f ? o0 : __expf(o0) - 1.0f;  // elu
  o1 = o1 > 0.f ? o1 : __expf(o1) - 1.0f;
  o2 = o2 > 0.f ? o2 : __expf(o2) - 1.0f;
  o3 = o3 > 0.f ? o3 : __expf(o3) - 1.0f;
  const float third = 1.0f / 3.0f;
  float* hp = hout + n * 256 + lane;
  if (accum) {
    hp[0] += o0 * third; hp[64] += o1 * third;
    hp[128] += o2 * third; hp[192] += o3 * third;
  } else {
    hp[0] = o0 * third; hp[64] = o1 * third;
    hp[128] = o2 * third; hp[192] = o3 * third;
  }
}

// ---------------- final mean over heads -> fp32 out ----------------

__global__ void mean_kernel(const float* __restrict__ h, float* __restrict__ out) {
  int i = blockIdx.x * 256 + threadIdx.x;  // over N*64
  int n = i >> 6, d = i & 63;
  const float* p = h + n * 256 + d;
  out[i] = 0.25f * (p[0] + p[64] + p[128] + p[192]);
}

// ---------------- launch ----------------

extern "C" void kernel_launch(void* const* d_in, const int* in_sizes, int n_in,
                              void* d_out, int out_size, void* d_ws, size_t ws_size,
                              hipStream_t stream) {
  (void)in_sizes; (void)n_in; (void)out_size; (void)ws_size;
  const float* x = (const float*)d_in[0];
  const int* src = (const int*)d_in[1];
  const int* dst = (const int*)d_in[2];
  const float* Wl[3]  = {(const float*)d_in[3], (const float*)d_in[7], (const float*)d_in[11]};
  const float* alL[3] = {(const float*)d_in[4], (const float*)d_in[8], (const float*)d_in[12]};
  const float* arL[3] = {(const float*)d_in[5], (const float*)d_in[9], (const float*)d_in[13]};
  const float* bL[3]  = {(const float*)d_in[6], (const float*)d_in[10], (const float*)d_in[14]};

  char* p = (char*)d_ws;
  auto alloc = [&](size_t bytes) {
    char* q = p;
    p += (bytes + 255) & ~size_t(255);
    return q;
  };
  float* hbuf0   = (float*)alloc((size_t)N_NODES * 256 * 4);
  float* hbuf1   = (float*)alloc((size_t)N_NODES * 256 * 4);
  float* feat    = (float*)alloc((size_t)N_NODES * 256 * 4);
  float* el      = (float*)alloc((size_t)N_NODES * 4 * 4);
  float* er      = (float*)alloc((size_t)N_NODES * 4 * 4);
  int*   cnt     = (int*)alloc((size_t)N_REL * N_NODES * 4);
  int*   cursor  = (int*)alloc((size_t)N_REL * N_NODES * 4);
  int*   row_ptr = (int*)alloc((size_t)N_REL * (N_NODES + 1) * 4);
  int*   col     = (int*)alloc((size_t)N_REL * N_EDGES * 4);

  hipMemsetAsync(cnt, 0, (size_t)N_REL * N_NODES * 4, stream);
  const int totalE = N_REL * N_EDGES;
  count_kernel<<<(totalE + 255) / 256, 256, 0, stream>>>(dst, cnt, totalE);
  scan_kernel<<<N_REL, 1024, 0, stream>>>(cnt, row_ptr, cursor);
  scatter_kernel<<<(totalE + 255) / 256, 256, 0, stream>>>(src, dst, cursor, col, totalE);

  const float* hin = x;
  float* houts[3] = {hbuf0, hbuf1, hbuf0};
  for (int l = 0; l < 3; l++) {
    float* hout = houts[l];
    for (int r = 0; r < 3; r++) {
      gemm_kernel<<<dim3((N_NODES + 127) / 128, 2), 256, 0, stream>>>(
          hin, Wl[l] + (size_t)r * 256 * 256, feat, N_NODES);
      elr_kernel<<<N_NODES / 4, 256, 0, stream>>>(feat, alL[l] + r * 256, arL[l] + r * 256,
                                                  el, er);
      agg_kernel<<<N_NODES / 4, 256, 0, stream>>>(feat, el, er,
                                                  row_ptr + r * (N_NODES + 1),
                                                  col + (size_t)r * N_EDGES,
                                                  bL[l] + r * 256, hout, r);
    }
    hin = hout;
  }
  mean_kernel<<<(N_NODES * 64) / 256, 256, 0, stream>>>(hin, (float*)d_out);
}

// Round 3
// 1628.178 us; speedup vs baseline: 1.3463x; 1.3463x over previous
//
#include <hip/hip_runtime.h>
#include <hip/hip_bf16.h>

#define N_NODES 50000
#define N_EDGES 400000
#define N_REL   3
#define NEG_SLOPE 0.2f
#define RP_STRIDE 50016           // row_ptr per-relation stride, 16B-aligned for int4
#define SCAN_BLOCKS 49            // ceil(50000/1024)

typedef __bf16 bf16x8 __attribute__((ext_vector_type(8)));
typedef float  f32x4  __attribute__((ext_vector_type(4)));

static __device__ __forceinline__ float bf2f(unsigned short u) {
  return __uint_as_float(((unsigned)u) << 16);
}
static __device__ __forceinline__ unsigned short f2bf(float f) {
  union { float f; unsigned u; } x; x.f = f;
  unsigned r = x.u + 0x7FFFu + ((x.u >> 16) & 1u);   // RNE (finite inputs)
  return (unsigned short)(r >> 16);
}

// ---------------- CSR build ----------------

__global__ void count_kernel(const int* __restrict__ dst, int* __restrict__ cnt, int total) {
  int i = blockIdx.x * 256 + threadIdx.x;
  if (i < total) {
    int r = i / N_EDGES;
    atomicAdd(&cnt[r * N_NODES + dst[i]], 1);
  }
}

// 147 blocks: per-block sum of 1024 counts
__global__ void block_reduce_kernel(const int* __restrict__ cnt, int* __restrict__ psum) {
  __shared__ int s[256];
  int r = blockIdx.x / SCAN_BLOCKS, b = blockIdx.x % SCAN_BLOCKS;
  int node = b * 1024 + threadIdx.x * 4;
  int sum = 0;
  if (node + 3 < N_NODES) {
    int4 v = *(const int4*)&cnt[r * N_NODES + node];
    sum = v.x + v.y + v.z + v.w;
  } else {
    for (int j = 0; j < 4; j++)
      if (node + j < N_NODES) sum += cnt[r * N_NODES + node + j];
  }
  s[threadIdx.x] = sum;
  __syncthreads();
  for (int o = 128; o > 0; o >>= 1) {
    if (threadIdx.x < o) s[threadIdx.x] += s[threadIdx.x + o];
    __syncthreads();
  }
  if (threadIdx.x == 0) psum[r * SCAN_BLOCKS + b] = s[0];
}

// 3 blocks x 64: exclusive scan of 49 partials per relation
__global__ void psum_scan_kernel(int* __restrict__ psum, int* __restrict__ row_ptr) {
  int r = blockIdx.x, t = threadIdx.x;
  int v = (t < SCAN_BLOCKS) ? psum[r * SCAN_BLOCKS + t] : 0;
  int incl = v;
#pragma unroll
  for (int o = 1; o < 64; o <<= 1) {
    int u = __shfl_up(incl, o);
    if (t >= o) incl += u;
  }
  if (t < SCAN_BLOCKS) psum[r * SCAN_BLOCKS + t] = incl - v;
  if (t == SCAN_BLOCKS - 1) row_ptr[r * RP_STRIDE + N_NODES] = incl;
}

// 147 blocks: block-local scan + global offset -> row_ptr, cursor
__global__ void scan_write_kernel(const int* __restrict__ cnt, const int* __restrict__ psum,
                                  int* __restrict__ row_ptr, int* __restrict__ cursor) {
  __shared__ int s[256];
  int r = blockIdx.x / SCAN_BLOCKS, b = blockIdx.x % SCAN_BLOCKS;
  int tid = threadIdx.x;
  int node = b * 1024 + tid * 4;
  int c[4] = {0, 0, 0, 0};
  if (node + 3 < N_NODES) {
    int4 v = *(const int4*)&cnt[r * N_NODES + node];
    c[0] = v.x; c[1] = v.y; c[2] = v.z; c[3] = v.w;
  } else {
    for (int j = 0; j < 4; j++)
      if (node + j < N_NODES) c[j] = cnt[r * N_NODES + node + j];
  }
  int tsum = c[0] + c[1] + c[2] + c[3];
  s[tid] = tsum;
  __syncthreads();
  for (int o = 1; o < 256; o <<= 1) {
    int v = (tid >= o) ? s[tid - o] : 0;
    __syncthreads();
    s[tid] += v;
    __syncthreads();
  }
  int run = s[tid] - tsum + psum[r * SCAN_BLOCKS + b];
  if (node + 3 < N_NODES) {
    int4 rp = make_int4(run, run + c[0], run + c[0] + c[1], run + c[0] + c[1] + c[2]);
    *(int4*)&row_ptr[r * RP_STRIDE + node] = rp;
    *(int4*)&cursor[r * N_NODES + node] = rp;
  } else {
    for (int j = 0; j < 4; j++) {
      if (node + j < N_NODES) {
        row_ptr[r * RP_STRIDE + node + j] = run;
        cursor[r * N_NODES + node + j] = run;
      }
      run += c[j];
    }
  }
}

__global__ void scatter_kernel(const int* __restrict__ src, const int* __restrict__ dst,
                               int* __restrict__ cursor, int* __restrict__ col, int total) {
  int i = blockIdx.x * 256 + threadIdx.x;
  if (i < total) {
    int r = i / N_EDGES;
    int d = dst[i];
    int pos = atomicAdd(&cursor[r * N_NODES + d], 1);
    col[r * N_EDGES + pos] = src[i];
  }
}

// ---------------- weight transpose + hi/lo bf16 split ----------------
// 9 matrices of 256x256: Wt[n][k] = W[k][n]; hi = bf16(w), lo = bf16(w - hi)

__global__ void wsplit_kernel(const float* __restrict__ W0, const float* __restrict__ W1,
                              const float* __restrict__ W2,
                              unsigned short* __restrict__ Whi, unsigned short* __restrict__ Wlo) {
  __shared__ float tile[32][33];
  int mat = blockIdx.x >> 6;           // 0..8
  int t = blockIdx.x & 63;
  int k0 = (t >> 3) * 32, n0 = (t & 7) * 32;
  const float* W = (mat < 3 ? W0 : (mat < 6 ? W1 : W2)) + (size_t)(mat % 3) * 65536;
  int row = threadIdx.x >> 3;          // 0..31 (k)
  int c4 = threadIdx.x & 7;            // 0..7
  float4 v = *(const float4*)&W[(k0 + row) * 256 + n0 + c4 * 4];
  tile[c4 * 4 + 0][row] = v.x;
  tile[c4 * 4 + 1][row] = v.y;
  tile[c4 * 4 + 2][row] = v.z;
  tile[c4 * 4 + 3][row] = v.w;
  __syncthreads();
  int nl = threadIdx.x >> 3;           // 0..31 (n)
  int kq = threadIdx.x & 7;
  ushort4 h, l;
  float a0 = tile[nl][kq * 4 + 0], a1 = tile[nl][kq * 4 + 1];
  float a2 = tile[nl][kq * 4 + 2], a3 = tile[nl][kq * 4 + 3];
  h.x = f2bf(a0); l.x = f2bf(a0 - bf2f(h.x));
  h.y = f2bf(a1); l.y = f2bf(a1 - bf2f(h.y));
  h.z = f2bf(a2); l.z = f2bf(a2 - bf2f(h.z));
  h.w = f2bf(a3); l.w = f2bf(a3 - bf2f(h.w));
  size_t o = (size_t)mat * 65536 + (n0 + nl) * 256 + k0 + kq * 4;
  *(ushort4*)&Whi[o] = h;
  *(ushort4*)&Wlo[o] = l;
}

// ---------------- GEMM: C(M,256) = A(M,256) * W(256,256), split-bf16 MFMA ----------------
// 128x128 tile, 256 thr = 4 waves, each wave 4x4 of 16x16x32 MFMA tiles,
// 3 MFMAs per tile per k-step (hi*hi + hi*lo + lo*hi) => ~fp32 accuracy.

__global__ __launch_bounds__(256, 2) void gemm_mfma_kernel(
    const float* __restrict__ A, const unsigned short* __restrict__ Bhi,
    const unsigned short* __restrict__ Blo, float* __restrict__ C, int M) {
  __shared__ unsigned short As_h[128 * 32], As_l[128 * 32];
  __shared__ unsigned short Bs_h[128 * 32], Bs_l[128 * 32];
  const int tid = threadIdx.x;
  const int wave = tid >> 6, lane = tid & 63;
  const int quad = lane >> 4, l16 = lane & 15;
  const int wr = wave & 1, wc = wave >> 1;     // wave quadrant in 128x128
  const int m0 = blockIdx.x * 128, n0 = blockIdx.y * 128;

  f32x4 acc[4][4];
#pragma unroll
  for (int i = 0; i < 4; i++)
#pragma unroll
    for (int j = 0; j < 4; j++) acc[i][j] = (f32x4){0.f, 0.f, 0.f, 0.f};

  for (int kb = 0; kb < 8; kb++) {
    int k0 = kb * 32;
    // A tile: 128x32 fp32 -> split to hi/lo bf16 in LDS
#pragma unroll
    for (int j = 0; j < 4; j++) {
      int f = tid + 256 * j;           // 0..1023
      int rr = f >> 3, kk = (f & 7) << 2;
      int gm = m0 + rr;
      float4 v = make_float4(0.f, 0.f, 0.f, 0.f);
      if (gm < M) v = *(const float4*)&A[gm * 256 + k0 + kk];
      ushort4 h, l;
      h.x = f2bf(v.x); l.x = f2bf(v.x - bf2f(h.x));
      h.y = f2bf(v.y); l.y = f2bf(v.y - bf2f(h.y));
      h.z = f2bf(v.z); l.z = f2bf(v.z - bf2f(h.z));
      h.w = f2bf(v.w); l.w = f2bf(v.w - bf2f(h.w));
      *(ushort4*)&As_h[rr * 32 + kk] = h;
      *(ushort4*)&As_l[rr * 32 + kk] = l;
    }
    // B tiles: already bf16 [n][k]; copy 128x32
#pragma unroll
    for (int j = 0; j < 2; j++) {
      int f = tid + 256 * j;           // 0..511
      int rr = f >> 2, kc = (f & 3) << 3;
      size_t go = (size_t)(n0 + rr) * 256 + k0 + kc;
      *(uint4*)&Bs_h[rr * 32 + kc] = *(const uint4*)&Bhi[go];
      *(uint4*)&Bs_l[rr * 32 + kc] = *(const uint4*)&Blo[go];
    }
    __syncthreads();

    bf16x8 ah[4], al[4], bh[4], bl[4];
#pragma unroll
    for (int t = 0; t < 4; t++) {
      int arow = (wr * 64 + t * 16 + l16) * 32 + quad * 8;
      int brow = (wc * 64 + t * 16 + l16) * 32 + quad * 8;
      ah[t] = *(const bf16x8*)&As_h[arow];
      al[t] = *(const bf16x8*)&As_l[arow];
      bh[t] = *(const bf16x8*)&Bs_h[brow];
      bl[t] = *(const bf16x8*)&Bs_l[brow];
    }
#pragma unroll
    for (int mi = 0; mi < 4; mi++)
#pragma unroll
      for (int ni = 0; ni < 4; ni++) {
        acc[mi][ni] = __builtin_amdgcn_mfma_f32_16x16x32_bf16(ah[mi], bl[ni], acc[mi][ni], 0, 0, 0);
        acc[mi][ni] = __builtin_amdgcn_mfma_f32_16x16x32_bf16(al[mi], bh[ni], acc[mi][ni], 0, 0, 0);
        acc[mi][ni] = __builtin_amdgcn_mfma_f32_16x16x32_bf16(ah[mi], bh[ni], acc[mi][ni], 0, 0, 0);
      }
    __syncthreads();
  }

  // C/D layout: row = quad*4 + reg, col = lane&15  [m91-verified]
#pragma unroll
  for (int mi = 0; mi < 4; mi++) {
    int rbase = m0 + wr * 64 + mi * 16 + quad * 4;
#pragma unroll
    for (int ni = 0; ni < 4; ni++) {
      int gc = n0 + wc * 64 + ni * 16 + l16;
#pragma unroll
      for (int r = 0; r < 4; r++) {
        int gm = rbase + r;
        if (gm < M) C[(size_t)gm * 256 + gc] = acc[mi][ni][r];
      }
    }
  }
}

// ---------------- el/er: per-node attention logits ----------------

__global__ void elr_kernel(const float* __restrict__ feat,
                           const float* __restrict__ al,
                           const float* __restrict__ ar,
                           float* __restrict__ el, float* __restrict__ er) {
  int node = blockIdx.x * 4 + (threadIdx.x >> 6);
  int lane = threadIdx.x & 63;
  if (node >= N_NODES) return;
  float e1[4], e2[4];
#pragma unroll
  for (int h = 0; h < 4; h++) {
    float v = feat[node * 256 + h * 64 + lane];
    e1[h] = v * al[h * 64 + lane];
    e2[h] = v * ar[h * 64 + lane];
  }
#pragma unroll
  for (int off = 32; off > 0; off >>= 1)
#pragma unroll
    for (int h = 0; h < 4; h++) {
      e1[h] += __shfl_down(e1[h], off);
      e2[h] += __shfl_down(e2[h], off);
    }
  if (lane == 0) {
    ((float4*)el)[node] = make_float4(e1[0], e1[1], e1[2], e1[3]);
    ((float4*)er)[node] = make_float4(e2[0], e2[1], e2[2], e2[3]);
  }
}

// ---------------- per-dst aggregation with online softmax ----------------

__global__ void agg_kernel(const float* __restrict__ feat,
                           const float* __restrict__ el, const float* __restrict__ er,
                           const int* __restrict__ row_ptr, const int* __restrict__ col,
                           const float* __restrict__ bias,
                           float* __restrict__ hout, int accum) {
  int n = blockIdx.x * 4 + (threadIdx.x >> 6);
  int lane = threadIdx.x & 63;
  if (n >= N_NODES) return;
  float4 ern = ((const float4*)er)[n];
  int s0 = row_ptr[n], s1 = row_ptr[n + 1];
  float m0 = -1e30f, m1 = -1e30f, m2 = -1e30f, m3 = -1e30f;
  float l0 = 0.f, l1 = 0.f, l2 = 0.f, l3 = 0.f;
  float a0 = 0.f, a1 = 0.f, a2 = 0.f, a3 = 0.f;
  for (int i = s0; i < s1; i++) {
    int s = col[i];
    float4 els = ((const float4*)el)[s];
    float e0 = els.x + ern.x; e0 = e0 > 0.f ? e0 : NEG_SLOPE * e0;
    float e1 = els.y + ern.y; e1 = e1 > 0.f ? e1 : NEG_SLOPE * e1;
    float e2 = els.z + ern.z; e2 = e2 > 0.f ? e2 : NEG_SLOPE * e2;
    float e3 = els.w + ern.w; e3 = e3 > 0.f ? e3 : NEG_SLOPE * e3;
    const float* fs = feat + (size_t)s * 256 + lane;
    float f0 = fs[0], f1 = fs[64], f2 = fs[128], f3 = fs[192];
    float nm;
    nm = fmaxf(m0, e0); { float sc = __expf(m0 - nm), p = __expf(e0 - nm);
      a0 = a0 * sc + p * f0; l0 = l0 * sc + p; m0 = nm; }
    nm = fmaxf(m1, e1); { float sc = __expf(m1 - nm), p = __expf(e1 - nm);
      a1 = a1 * sc + p * f1; l1 = l1 * sc + p; m1 = nm; }
    nm = fmaxf(m2, e2); { float sc = __expf(m2 - nm), p = __expf(e2 - nm);
      a2 = a2 * sc + p * f2; l2 = l2 * sc + p; m2 = nm; }
    nm = fmaxf(m3, e3); { float sc = __expf(m3 - nm), p = __expf(e3 - nm);
      a3 = a3 * sc + p * f3; l3 = l3 * sc + p; m3 = nm; }
  }
  float o0 = a0 / fmaxf(l0, 1e-9f) + bias[0 * 64 + lane];
  float o1 = a1 / fmaxf(l1, 1e-9f) + bias[1 * 64 + lane];
  float o2 = a2 / fmaxf(l2, 1e-9f) + bias[2 * 64 + lane];
  float o3 = a3 / fmaxf(l3, 1e-9f) + bias[3 * 64 + lane];
  o0 = o0 > 0.f ? o0 : __expf(o0) - 1.0f;  // elu
  o1 = o1 > 0.f ? o1 : __expf(o1) - 1.0f;
  o2 = o2 > 0.f ? o2 : __expf(o2) - 1.0f;
  o3 = o3 > 0.f ? o3 : __expf(o3) - 1.0f;
  const float third = 1.0f / 3.0f;
  float* hp = hout + (size_t)n * 256 + lane;
  if (accum) {
    hp[0] += o0 * third; hp[64] += o1 * third;
    hp[128] += o2 * third; hp[192] += o3 * third;
  } else {
    hp[0] = o0 * third; hp[64] = o1 * third;
    hp[128] = o2 * third; hp[192] = o3 * third;
  }
}

// ---------------- final mean over heads -> fp32 out ----------------

__global__ void mean_kernel(const float* __restrict__ h, float* __restrict__ out) {
  int i = blockIdx.x * 256 + threadIdx.x;  // over N*64
  int n = i >> 6, d = i & 63;
  const float* p = h + (size_t)n * 256 + d;
  out[i] = 0.25f * (p[0] + p[64] + p[128] + p[192]);
}

// ---------------- launch ----------------

extern "C" void kernel_launch(void* const* d_in, const int* in_sizes, int n_in,
                              void* d_out, int out_size, void* d_ws, size_t ws_size,
                              hipStream_t stream) {
  (void)in_sizes; (void)n_in; (void)out_size; (void)ws_size;
  const float* x = (const float*)d_in[0];
  const int* src = (const int*)d_in[1];
  const int* dst = (const int*)d_in[2];
  const float* Wl[3]  = {(const float*)d_in[3], (const float*)d_in[7], (const float*)d_in[11]};
  const float* alL[3] = {(const float*)d_in[4], (const float*)d_in[8], (const float*)d_in[12]};
  const float* arL[3] = {(const float*)d_in[5], (const float*)d_in[9], (const float*)d_in[13]};
  const float* bL[3]  = {(const float*)d_in[6], (const float*)d_in[10], (const float*)d_in[14]};

  char* p = (char*)d_ws;
  auto alloc = [&](size_t bytes) {
    char* q = p;
    p += (bytes + 255) & ~size_t(255);
    return q;
  };
  float* hbuf0   = (float*)alloc((size_t)N_NODES * 256 * 4);
  float* hbuf1   = (float*)alloc((size_t)N_NODES * 256 * 4);
  float* feat    = (float*)alloc((size_t)N_NODES * 256 * 4);
  float* el      = (float*)alloc((size_t)N_NODES * 4 * 4);
  float* er      = (float*)alloc((size_t)N_NODES * 4 * 4);
  int*   cnt     = (int*)alloc((size_t)N_REL * N_NODES * 4);
  int*   cursor  = (int*)alloc((size_t)N_REL * N_NODES * 4);
  int*   row_ptr = (int*)alloc((size_t)N_REL * RP_STRIDE * 4 + 64);
  int*   col     = (int*)alloc((size_t)N_REL * N_EDGES * 4);
  int*   psum    = (int*)alloc((size_t)N_REL * SCAN_BLOCKS * 4);
  unsigned short* Whi = (unsigned short*)alloc((size_t)9 * 65536 * 2);
  unsigned short* Wlo = (unsigned short*)alloc((size_t)9 * 65536 * 2);

  hipMemsetAsync(cnt, 0, (size_t)N_REL * N_NODES * 4, stream);
  const int totalE = N_REL * N_EDGES;
  count_kernel<<<(totalE + 255) / 256, 256, 0, stream>>>(dst, cnt, totalE);
  block_reduce_kernel<<<N_REL * SCAN_BLOCKS, 256, 0, stream>>>(cnt, psum);
  psum_scan_kernel<<<N_REL, 64, 0, stream>>>(psum, row_ptr);
  scan_write_kernel<<<N_REL * SCAN_BLOCKS, 256, 0, stream>>>(cnt, psum, row_ptr, cursor);
  scatter_kernel<<<(totalE + 255) / 256, 256, 0, stream>>>(src, dst, cursor, col, totalE);
  wsplit_kernel<<<9 * 64, 256, 0, stream>>>(Wl[0], Wl[1], Wl[2], Whi, Wlo);

  const float* hin = x;
  float* houts[3] = {hbuf0, hbuf1, hbuf0};
  for (int l = 0; l < 3; l++) {
    float* hout = houts[l];
    for (int r = 0; r < 3; r++) {
      const unsigned short* bh = Whi + (size_t)(l * 3 + r) * 65536;
      const unsigned short* bl = Wlo + (size_t)(l * 3 + r) * 65536;
      gemm_mfma_kernel<<<dim3((N_NODES + 127) / 128, 2), 256, 0, stream>>>(
          hin, bh, bl, feat, N_NODES);
      elr_kernel<<<N_NODES / 4, 256, 0, stream>>>(feat, alL[l] + r * 256, arL[l] + r * 256,
                                                  el, er);
      agg_kernel<<<N_NODES / 4, 256, 0, stream>>>(feat, el, er,
                                                  row_ptr + r * RP_STRIDE,
                                                  col + (size_t)r * N_EDGES,
                                                  bL[l] + r * 256, hout, r);
    }
    hin = hout;
  }
  mean_kernel<<<(N_NODES * 64) / 256, 256, 0, stream>>>(hin, (float*)d_out);
}

// Round 4
// 1270.076 us; speedup vs baseline: 1.7259x; 1.2820x over previous
//
#include <hip/hip_runtime.h>
#include <hip/hip_bf16.h>

#define N_NODES 50000
#define N_EDGES 400000
#define N_REL   3
#define NEG_SLOPE 0.2f
#define RP_STRIDE 50016           // row_ptr per-relation stride, 16B-aligned for int4
#define SCAN_BLOCKS 49            // ceil(50000/1024)

typedef __bf16 bf16x8 __attribute__((ext_vector_type(8)));
typedef float  f32x4  __attribute__((ext_vector_type(4)));

static __device__ __forceinline__ float bf2f(unsigned short u) {
  return __uint_as_float(((unsigned)u) << 16);
}
static __device__ __forceinline__ unsigned short f2bf(float f) {
  union { float f; unsigned u; } x; x.f = f;
  unsigned r = x.u + 0x7FFFu + ((x.u >> 16) & 1u);   // RNE (finite inputs)
  return (unsigned short)(r >> 16);
}

// ---------------- CSR build ----------------

__global__ void count_kernel(const int* __restrict__ dst, int* __restrict__ cnt, int total) {
  int i = blockIdx.x * 256 + threadIdx.x;
  if (i < total) {
    int r = i / N_EDGES;
    atomicAdd(&cnt[r * N_NODES + dst[i]], 1);
  }
}

__global__ void block_reduce_kernel(const int* __restrict__ cnt, int* __restrict__ psum) {
  __shared__ int s[256];
  int r = blockIdx.x / SCAN_BLOCKS, b = blockIdx.x % SCAN_BLOCKS;
  int node = b * 1024 + threadIdx.x * 4;
  int sum = 0;
  if (node + 3 < N_NODES) {
    int4 v = *(const int4*)&cnt[r * N_NODES + node];
    sum = v.x + v.y + v.z + v.w;
  } else {
    for (int j = 0; j < 4; j++)
      if (node + j < N_NODES) sum += cnt[r * N_NODES + node + j];
  }
  s[threadIdx.x] = sum;
  __syncthreads();
  for (int o = 128; o > 0; o >>= 1) {
    if (threadIdx.x < o) s[threadIdx.x] += s[threadIdx.x + o];
    __syncthreads();
  }
  if (threadIdx.x == 0) psum[r * SCAN_BLOCKS + b] = s[0];
}

__global__ void psum_scan_kernel(int* __restrict__ psum, int* __restrict__ row_ptr) {
  int r = blockIdx.x, t = threadIdx.x;
  int v = (t < SCAN_BLOCKS) ? psum[r * SCAN_BLOCKS + t] : 0;
  int incl = v;
#pragma unroll
  for (int o = 1; o < 64; o <<= 1) {
    int u = __shfl_up(incl, o);
    if (t >= o) incl += u;
  }
  if (t < SCAN_BLOCKS) psum[r * SCAN_BLOCKS + t] = incl - v;
  if (t == SCAN_BLOCKS - 1) row_ptr[r * RP_STRIDE + N_NODES] = incl;
}

__global__ void scan_write_kernel(const int* __restrict__ cnt, const int* __restrict__ psum,
                                  int* __restrict__ row_ptr, int* __restrict__ cursor) {
  __shared__ int s[256];
  int r = blockIdx.x / SCAN_BLOCKS, b = blockIdx.x % SCAN_BLOCKS;
  int tid = threadIdx.x;
  int node = b * 1024 + tid * 4;
  int c[4] = {0, 0, 0, 0};
  if (node + 3 < N_NODES) {
    int4 v = *(const int4*)&cnt[r * N_NODES + node];
    c[0] = v.x; c[1] = v.y; c[2] = v.z; c[3] = v.w;
  } else {
    for (int j = 0; j < 4; j++)
      if (node + j < N_NODES) c[j] = cnt[r * N_NODES + node + j];
  }
  int tsum = c[0] + c[1] + c[2] + c[3];
  s[tid] = tsum;
  __syncthreads();
  for (int o = 1; o < 256; o <<= 1) {
    int v = (tid >= o) ? s[tid - o] : 0;
    __syncthreads();
    s[tid] += v;
    __syncthreads();
  }
  int run = s[tid] - tsum + psum[r * SCAN_BLOCKS + b];
  if (node + 3 < N_NODES) {
    int4 rp = make_int4(run, run + c[0], run + c[0] + c[1], run + c[0] + c[1] + c[2]);
    *(int4*)&row_ptr[r * RP_STRIDE + node] = rp;
    *(int4*)&cursor[r * N_NODES + node] = rp;
  } else {
    for (int j = 0; j < 4; j++) {
      if (node + j < N_NODES) {
        row_ptr[r * RP_STRIDE + node + j] = run;
        cursor[r * N_NODES + node + j] = run;
      }
      run += c[j];
    }
  }
}

__global__ void scatter_kernel(const int* __restrict__ src, const int* __restrict__ dst,
                               int* __restrict__ cursor, int* __restrict__ col, int total) {
  int i = blockIdx.x * 256 + threadIdx.x;
  if (i < total) {
    int r = i / N_EDGES;
    int d = dst[i];
    int pos = atomicAdd(&cursor[r * N_NODES + d], 1);
    col[r * N_EDGES + pos] = src[i];
  }
}

// ---------------- weight transpose + hi/lo bf16 split ----------------

__global__ void wsplit_kernel(const float* __restrict__ W0, const float* __restrict__ W1,
                              const float* __restrict__ W2,
                              unsigned short* __restrict__ Whi, unsigned short* __restrict__ Wlo) {
  __shared__ float tile[32][33];
  int mat = blockIdx.x >> 6;           // 0..8
  int t = blockIdx.x & 63;
  int k0 = (t >> 3) * 32, n0 = (t & 7) * 32;
  const float* W = (mat < 3 ? W0 : (mat < 6 ? W1 : W2)) + (size_t)(mat % 3) * 65536;
  int row = threadIdx.x >> 3;          // 0..31 (k)
  int c4 = threadIdx.x & 7;            // 0..7
  float4 v = *(const float4*)&W[(k0 + row) * 256 + n0 + c4 * 4];
  tile[c4 * 4 + 0][row] = v.x;
  tile[c4 * 4 + 1][row] = v.y;
  tile[c4 * 4 + 2][row] = v.z;
  tile[c4 * 4 + 3][row] = v.w;
  __syncthreads();
  int nl = threadIdx.x >> 3;           // 0..31 (n)
  int kq = threadIdx.x & 7;
  ushort4 h, l;
  float a0 = tile[nl][kq * 4 + 0], a1 = tile[nl][kq * 4 + 1];
  float a2 = tile[nl][kq * 4 + 2], a3 = tile[nl][kq * 4 + 3];
  h.x = f2bf(a0); l.x = f2bf(a0 - bf2f(h.x));
  h.y = f2bf(a1); l.y = f2bf(a1 - bf2f(h.y));
  h.z = f2bf(a2); l.z = f2bf(a2 - bf2f(h.z));
  h.w = f2bf(a3); l.w = f2bf(a3 - bf2f(h.w));
  size_t o = (size_t)mat * 65536 + (n0 + nl) * 256 + k0 + kq * 4;
  *(ushort4*)&Whi[o] = h;
  *(ushort4*)&Wlo[o] = l;
}

// ---------------- GEMM + fused el/er + bf16 feat out ----------------
// 128x128 tile, 4 waves, split-bf16 3-MFMA fp32-accuracy GEMM.
// Epilogue: (a) el/er per row: each wave's 64 cols = exactly one head
// (head = by*2+wc) -> 16-lane shuffle reduce -> plain stores, no atomics.
// (b) feat -> bf16 via LDS transpose -> coalesced 16B stores.

#define LDT 136   // transpose row stride (ushorts); 272B keeps 16B alignment

__global__ __launch_bounds__(256, 2) void gemm_mfma_kernel(
    const float* __restrict__ A, const unsigned short* __restrict__ Bhi,
    const unsigned short* __restrict__ Blo, const float* __restrict__ alf,
    const float* __restrict__ arf, unsigned short* __restrict__ Cb,
    float* __restrict__ el, float* __restrict__ er, int M) {
  __shared__ __align__(16) unsigned short lds[128 * LDT];  // 34816 B >= 32768 B
  unsigned short* As_h = lds;
  unsigned short* As_l = lds + 128 * 32;
  unsigned short* Bs_h = lds + 2 * 128 * 32;
  unsigned short* Bs_l = lds + 3 * 128 * 32;

  const int tid = threadIdx.x;
  const int wave = tid >> 6, lane = tid & 63;
  const int quad = lane >> 4, l16 = lane & 15;
  const int wr = wave & 1, wc = wave >> 1;
  const int m0 = blockIdx.x * 128, n0 = blockIdx.y * 128;

  f32x4 acc[4][4];
#pragma unroll
  for (int i = 0; i < 4; i++)
#pragma unroll
    for (int j = 0; j < 4; j++) acc[i][j] = (f32x4){0.f, 0.f, 0.f, 0.f};

  for (int kb = 0; kb < 8; kb++) {
    int k0 = kb * 32;
#pragma unroll
    for (int j = 0; j < 4; j++) {
      int f = tid + 256 * j;
      int rr = f >> 3, kk = (f & 7) << 2;
      int gm = m0 + rr;
      float4 v = make_float4(0.f, 0.f, 0.f, 0.f);
      if (gm < M) v = *(const float4*)&A[(size_t)gm * 256 + k0 + kk];
      ushort4 h, l;
      h.x = f2bf(v.x); l.x = f2bf(v.x - bf2f(h.x));
      h.y = f2bf(v.y); l.y = f2bf(v.y - bf2f(h.y));
      h.z = f2bf(v.z); l.z = f2bf(v.z - bf2f(h.z));
      h.w = f2bf(v.w); l.w = f2bf(v.w - bf2f(h.w));
      *(ushort4*)&As_h[rr * 32 + kk] = h;
      *(ushort4*)&As_l[rr * 32 + kk] = l;
    }
#pragma unroll
    for (int j = 0; j < 2; j++) {
      int f = tid + 256 * j;
      int rr = f >> 2, kc = (f & 3) << 3;
      size_t go = (size_t)(n0 + rr) * 256 + k0 + kc;
      *(uint4*)&Bs_h[rr * 32 + kc] = *(const uint4*)&Bhi[go];
      *(uint4*)&Bs_l[rr * 32 + kc] = *(const uint4*)&Blo[go];
    }
    __syncthreads();

    bf16x8 ah[4], al_[4], bh[4], bl[4];
#pragma unroll
    for (int t = 0; t < 4; t++) {
      int arow = (wr * 64 + t * 16 + l16) * 32 + quad * 8;
      int brow = (wc * 64 + t * 16 + l16) * 32 + quad * 8;
      ah[t] = *(const bf16x8*)&As_h[arow];
      al_[t] = *(const bf16x8*)&As_l[arow];
      bh[t] = *(const bf16x8*)&Bs_h[brow];
      bl[t] = *(const bf16x8*)&Bs_l[brow];
    }
#pragma unroll
    for (int mi = 0; mi < 4; mi++)
#pragma unroll
      for (int ni = 0; ni < 4; ni++) {
        acc[mi][ni] = __builtin_amdgcn_mfma_f32_16x16x32_bf16(ah[mi], bl[ni], acc[mi][ni], 0, 0, 0);
        acc[mi][ni] = __builtin_amdgcn_mfma_f32_16x16x32_bf16(al_[mi], bh[ni], acc[mi][ni], 0, 0, 0);
        acc[mi][ni] = __builtin_amdgcn_mfma_f32_16x16x32_bf16(ah[mi], bh[ni], acc[mi][ni], 0, 0, 0);
      }
    __syncthreads();
  }

  // ---- fused el/er: this wave's 64 cols = head hw = by*2 + wc ----
  const int hw = (n0 >> 6) + wc;
  float alw[4], arw[4];
#pragma unroll
  for (int ni = 0; ni < 4; ni++) {
    int gc = n0 + wc * 64 + ni * 16 + l16;
    alw[ni] = alf[gc]; arw[ni] = arf[gc];
  }
  float pel[4][4], per_[4][4];
#pragma unroll
  for (int mi = 0; mi < 4; mi++)
#pragma unroll
    for (int r = 0; r < 4; r++) {
      float se = 0.f, sr = 0.f;
#pragma unroll
      for (int ni = 0; ni < 4; ni++) {
        se += acc[mi][ni][r] * alw[ni];
        sr += acc[mi][ni][r] * arw[ni];
      }
      pel[mi][r] = se; per_[mi][r] = sr;
    }
#pragma unroll
  for (int off = 1; off < 16; off <<= 1)
#pragma unroll
    for (int mi = 0; mi < 4; mi++)
#pragma unroll
      for (int r = 0; r < 4; r++) {
        pel[mi][r] += __shfl_xor(pel[mi][r], off);
        per_[mi][r] += __shfl_xor(per_[mi][r], off);
      }
  if (l16 == 0) {
#pragma unroll
    for (int mi = 0; mi < 4; mi++)
#pragma unroll
      for (int r = 0; r < 4; r++) {
        int gm = m0 + wr * 64 + mi * 16 + quad * 4 + r;
        if (gm < M) {
          el[gm * 4 + hw] = pel[mi][r];
          er[gm * 4 + hw] = per_[mi][r];
        }
      }
  }

  // ---- feat -> bf16 via LDS transpose, coalesced store ----
  // (safe: all LDS reads of the k-loop completed at its final barrier)
#pragma unroll
  for (int mi = 0; mi < 4; mi++) {
    int row = wr * 64 + mi * 16 + quad * 4;
#pragma unroll
    for (int ni = 0; ni < 4; ni++) {
      int c = wc * 64 + ni * 16 + l16;
#pragma unroll
      for (int r = 0; r < 4; r++)
        lds[(row + r) * LDT + c] = f2bf(acc[mi][ni][r]);
    }
  }
  __syncthreads();
#pragma unroll
  for (int it = 0; it < 8; it++) {
    int chunk = tid + 256 * it;           // 0..2047
    int row = chunk >> 4, c8 = (chunk & 15) * 8;
    int gm = m0 + row;
    if (gm < M)
      *(uint4*)&Cb[(size_t)gm * 256 + n0 + c8] = *(const uint4*)&lds[row * LDT + c8];
  }
}

// ---------------- per-dst aggregation, plain-exp softmax, bf16 gather ----------------

__global__ void agg_kernel(const unsigned short* __restrict__ featb,
                           const float* __restrict__ el, const float* __restrict__ er,
                           const int* __restrict__ row_ptr, const int* __restrict__ col,
                           const float* __restrict__ bias,
                           float* __restrict__ hout, int accum) {
  int n = blockIdx.x * 4 + (threadIdx.x >> 6);
  int lane = threadIdx.x & 63;
  if (n >= N_NODES) return;
  float4 ern = ((const float4*)er)[n];
  int s0 = row_ptr[n], s1 = row_ptr[n + 1];
  float l0 = 0.f, l1 = 0.f, l2 = 0.f, l3 = 0.f;
  float a0 = 0.f, a1 = 0.f, a2 = 0.f, a3 = 0.f;
  for (int i = s0; i < s1; i++) {
    int s = col[i];
    float4 els = ((const float4*)el)[s];
    float e0 = els.x + ern.x; e0 = e0 > 0.f ? e0 : NEG_SLOPE * e0;
    float e1 = els.y + ern.y; e1 = e1 > 0.f ? e1 : NEG_SLOPE * e1;
    float e2 = els.z + ern.z; e2 = e2 > 0.f ? e2 : NEG_SLOPE * e2;
    float e3 = els.w + ern.w; e3 = e3 > 0.f ? e3 : NEG_SLOPE * e3;
    // softmax is shift-invariant; logits are O(few) -> plain exp is exact-equivalent
    float p0 = __expf(e0), p1 = __expf(e1), p2 = __expf(e2), p3 = __expf(e3);
    const unsigned short* fs = featb + (size_t)s * 256 + lane;
    a0 += p0 * bf2f(fs[0]);   l0 += p0;
    a1 += p1 * bf2f(fs[64]);  l1 += p1;
    a2 += p2 * bf2f(fs[128]); l2 += p2;
    a3 += p3 * bf2f(fs[192]); l3 += p3;
  }
  float o0 = a0 / fmaxf(l0, 1e-30f) + bias[0 * 64 + lane];
  float o1 = a1 / fmaxf(l1, 1e-30f) + bias[1 * 64 + lane];
  float o2 = a2 / fmaxf(l2, 1e-30f) + bias[2 * 64 + lane];
  float o3 = a3 / fmaxf(l3, 1e-30f) + bias[3 * 64 + lane];
  o0 = o0 > 0.f ? o0 : __expf(o0) - 1.0f;  // elu
  o1 = o1 > 0.f ? o1 : __expf(o1) - 1.0f;
  o2 = o2 > 0.f ? o2 : __expf(o2) - 1.0f;
  o3 = o3 > 0.f ? o3 : __expf(o3) - 1.0f;
  const float third = 1.0f / 3.0f;
  float* hp = hout + (size_t)n * 256 + lane;
  if (accum) {
    hp[0] += o0 * third; hp[64] += o1 * third;
    hp[128] += o2 * third; hp[192] += o3 * third;
  } else {
    hp[0] = o0 * third; hp[64] = o1 * third;
    hp[128] = o2 * third; hp[192] = o3 * third;
  }
}

// ---------------- final mean over heads -> fp32 out ----------------

__global__ void mean_kernel(const float* __restrict__ h, float* __restrict__ out) {
  int i = blockIdx.x * 256 + threadIdx.x;  // over N*64
  int n = i >> 6, d = i & 63;
  const float* p = h + (size_t)n * 256 + d;
  out[i] = 0.25f * (p[0] + p[64] + p[128] + p[192]);
}

// ---------------- launch ----------------

extern "C" void kernel_launch(void* const* d_in, const int* in_sizes, int n_in,
                              void* d_out, int out_size, void* d_ws, size_t ws_size,
                              hipStream_t stream) {
  (void)in_sizes; (void)n_in; (void)out_size; (void)ws_size;
  const float* x = (const float*)d_in[0];
  const int* src = (const int*)d_in[1];
  const int* dst = (const int*)d_in[2];
  const float* Wl[3]  = {(const float*)d_in[3], (const float*)d_in[7], (const float*)d_in[11]};
  const float* alL[3] = {(const float*)d_in[4], (const float*)d_in[8], (const float*)d_in[12]};
  const float* arL[3] = {(const float*)d_in[5], (const float*)d_in[9], (const float*)d_in[13]};
  const float* bL[3]  = {(const float*)d_in[6], (const float*)d_in[10], (const float*)d_in[14]};

  char* p = (char*)d_ws;
  auto alloc = [&](size_t bytes) {
    char* q = p;
    p += (bytes + 255) & ~size_t(255);
    return q;
  };
  float* hbuf0   = (float*)alloc((size_t)N_NODES * 256 * 4);
  float* hbuf1   = (float*)alloc((size_t)N_NODES * 256 * 4);
  unsigned short* featb = (unsigned short*)alloc((size_t)N_NODES * 256 * 2);
  float* el      = (float*)alloc((size_t)N_NODES * 4 * 4);
  float* er      = (float*)alloc((size_t)N_NODES * 4 * 4);
  int*   cnt     = (int*)alloc((size_t)N_REL * N_NODES * 4);
  int*   cursor  = (int*)alloc((size_t)N_REL * N_NODES * 4);
  int*   row_ptr = (int*)alloc((size_t)N_REL * RP_STRIDE * 4 + 64);
  int*   col     = (int*)alloc((size_t)N_REL * N_EDGES * 4);
  int*   psum    = (int*)alloc((size_t)N_REL * SCAN_BLOCKS * 4);
  unsigned short* Whi = (unsigned short*)alloc((size_t)9 * 65536 * 2);
  unsigned short* Wlo = (unsigned short*)alloc((size_t)9 * 65536 * 2);

  hipMemsetAsync(cnt, 0, (size_t)N_REL * N_NODES * 4, stream);
  const int totalE = N_REL * N_EDGES;
  count_kernel<<<(totalE + 255) / 256, 256, 0, stream>>>(dst, cnt, totalE);
  block_reduce_kernel<<<N_REL * SCAN_BLOCKS, 256, 0, stream>>>(cnt, psum);
  psum_scan_kernel<<<N_REL, 64, 0, stream>>>(psum, row_ptr);
  scan_write_kernel<<<N_REL * SCAN_BLOCKS, 256, 0, stream>>>(cnt, psum, row_ptr, cursor);
  scatter_kernel<<<(totalE + 255) / 256, 256, 0, stream>>>(src, dst, cursor, col, totalE);
  wsplit_kernel<<<9 * 64, 256, 0, stream>>>(Wl[0], Wl[1], Wl[2], Whi, Wlo);

  const float* hin = x;
  float* houts[3] = {hbuf0, hbuf1, hbuf0};
  for (int l = 0; l < 3; l++) {
    float* hout = houts[l];
    for (int r = 0; r < 3; r++) {
      const unsigned short* bh = Whi + (size_t)(l * 3 + r) * 65536;
      const unsigned short* blo = Wlo + (size_t)(l * 3 + r) * 65536;
      gemm_mfma_kernel<<<dim3((N_NODES + 127) / 128, 2), 256, 0, stream>>>(
          hin, bh, blo, alL[l] + r * 256, arL[l] + r * 256, featb, el, er, N_NODES);
      agg_kernel<<<N_NODES / 4, 256, 0, stream>>>(featb, el, er,
                                                  row_ptr + r * RP_STRIDE,
                                                  col + (size_t)r * N_EDGES,
                                                  bL[l] + r * 256, hout, r);
    }
    hin = hout;
  }
  mean_kernel<<<(N_NODES * 64) / 256, 256, 0, stream>>>(hin, (float*)d_out);
}

// Round 5
// 1038.072 us; speedup vs baseline: 2.1116x; 1.2235x over previous
//
#include <hip/hip_runtime.h>
#include <hip/hip_bf16.h>

#define N_NODES 50000
#define N_EDGES 400000
#define N_REL   3
#define NEG_SLOPE 0.2f
#define RP_STRIDE 50016           // row_ptr per-relation stride, 16B-aligned for int4
#define SCAN_BLOCKS 49            // ceil(50000/1024)

typedef __bf16 bf16x8 __attribute__((ext_vector_type(8)));
typedef float  f32x4  __attribute__((ext_vector_type(4)));

static __device__ __forceinline__ float bf2f(unsigned short u) {
  return __uint_as_float(((unsigned)u) << 16);
}
static __device__ __forceinline__ unsigned short f2bf(float f) {
  union { float f; unsigned u; } x; x.f = f;
  unsigned r = x.u + 0x7FFFu + ((x.u >> 16) & 1u);   // RNE (finite inputs)
  return (unsigned short)(r >> 16);
}

// ---------------- CSR build ----------------

__global__ void count_kernel(const int* __restrict__ dst, int* __restrict__ cnt, int total) {
  int i = blockIdx.x * 256 + threadIdx.x;
  if (i < total) {
    int r = i / N_EDGES;
    atomicAdd(&cnt[r * N_NODES + dst[i]], 1);
  }
}

__global__ void block_reduce_kernel(const int* __restrict__ cnt, int* __restrict__ psum) {
  __shared__ int s[256];
  int r = blockIdx.x / SCAN_BLOCKS, b = blockIdx.x % SCAN_BLOCKS;
  int node = b * 1024 + threadIdx.x * 4;
  int sum = 0;
  if (node + 3 < N_NODES) {
    int4 v = *(const int4*)&cnt[r * N_NODES + node];
    sum = v.x + v.y + v.z + v.w;
  } else {
    for (int j = 0; j < 4; j++)
      if (node + j < N_NODES) sum += cnt[r * N_NODES + node + j];
  }
  s[threadIdx.x] = sum;
  __syncthreads();
  for (int o = 128; o > 0; o >>= 1) {
    if (threadIdx.x < o) s[threadIdx.x] += s[threadIdx.x + o];
    __syncthreads();
  }
  if (threadIdx.x == 0) psum[r * SCAN_BLOCKS + b] = s[0];
}

__global__ void psum_scan_kernel(int* __restrict__ psum, int* __restrict__ row_ptr) {
  int r = blockIdx.x, t = threadIdx.x;
  int v = (t < SCAN_BLOCKS) ? psum[r * SCAN_BLOCKS + t] : 0;
  int incl = v;
#pragma unroll
  for (int o = 1; o < 64; o <<= 1) {
    int u = __shfl_up(incl, o);
    if (t >= o) incl += u;
  }
  if (t < SCAN_BLOCKS) psum[r * SCAN_BLOCKS + t] = incl - v;
  if (t == SCAN_BLOCKS - 1) row_ptr[r * RP_STRIDE + N_NODES] = incl;
}

__global__ void scan_write_kernel(const int* __restrict__ cnt, const int* __restrict__ psum,
                                  int* __restrict__ row_ptr, int* __restrict__ cursor) {
  __shared__ int s[256];
  int r = blockIdx.x / SCAN_BLOCKS, b = blockIdx.x % SCAN_BLOCKS;
  int tid = threadIdx.x;
  int node = b * 1024 + tid * 4;
  int c[4] = {0, 0, 0, 0};
  if (node + 3 < N_NODES) {
    int4 v = *(const int4*)&cnt[r * N_NODES + node];
    c[0] = v.x; c[1] = v.y; c[2] = v.z; c[3] = v.w;
  } else {
    for (int j = 0; j < 4; j++)
      if (node + j < N_NODES) c[j] = cnt[r * N_NODES + node + j];
  }
  int tsum = c[0] + c[1] + c[2] + c[3];
  s[tid] = tsum;
  __syncthreads();
  for (int o = 1; o < 256; o <<= 1) {
    int v = (tid >= o) ? s[tid - o] : 0;
    __syncthreads();
    s[tid] += v;
    __syncthreads();
  }
  int run = s[tid] - tsum + psum[r * SCAN_BLOCKS + b];
  if (node + 3 < N_NODES) {
    int4 rp = make_int4(run, run + c[0], run + c[0] + c[1], run + c[0] + c[1] + c[2]);
    *(int4*)&row_ptr[r * RP_STRIDE + node] = rp;
    *(int4*)&cursor[r * N_NODES + node] = rp;
  } else {
    for (int j = 0; j < 4; j++) {
      if (node + j < N_NODES) {
        row_ptr[r * RP_STRIDE + node + j] = run;
        cursor[r * N_NODES + node + j] = run;
      }
      run += c[j];
    }
  }
}

__global__ void scatter_kernel(const int* __restrict__ src, const int* __restrict__ dst,
                               int* __restrict__ cursor, int* __restrict__ col, int total) {
  int i = blockIdx.x * 256 + threadIdx.x;
  if (i < total) {
    int r = i / N_EDGES;
    int d = dst[i];
    int pos = atomicAdd(&cursor[r * N_NODES + d], 1);
    col[r * N_EDGES + pos] = src[i];
  }
}

// ---------------- weight transpose + hi/lo bf16 split ----------------
// output layout: [mat=l*3+r][n 0..255][k 0..255] == per-layer merged [col 0..767][k]

__global__ void wsplit_kernel(const float* __restrict__ W0, const float* __restrict__ W1,
                              const float* __restrict__ W2,
                              unsigned short* __restrict__ Whi, unsigned short* __restrict__ Wlo) {
  __shared__ float tile[32][33];
  int mat = blockIdx.x >> 6;           // 0..8
  int t = blockIdx.x & 63;
  int k0 = (t >> 3) * 32, n0 = (t & 7) * 32;
  const float* W = (mat < 3 ? W0 : (mat < 6 ? W1 : W2)) + (size_t)(mat % 3) * 65536;
  int row = threadIdx.x >> 3;          // 0..31 (k)
  int c4 = threadIdx.x & 7;            // 0..7
  float4 v = *(const float4*)&W[(k0 + row) * 256 + n0 + c4 * 4];
  tile[c4 * 4 + 0][row] = v.x;
  tile[c4 * 4 + 1][row] = v.y;
  tile[c4 * 4 + 2][row] = v.z;
  tile[c4 * 4 + 3][row] = v.w;
  __syncthreads();
  int nl = threadIdx.x >> 3;           // 0..31 (n)
  int kq = threadIdx.x & 7;
  ushort4 h, l;
  float a0 = tile[nl][kq * 4 + 0], a1 = tile[nl][kq * 4 + 1];
  float a2 = tile[nl][kq * 4 + 2], a3 = tile[nl][kq * 4 + 3];
  h.x = f2bf(a0); l.x = f2bf(a0 - bf2f(h.x));
  h.y = f2bf(a1); l.y = f2bf(a1 - bf2f(h.y));
  h.z = f2bf(a2); l.z = f2bf(a2 - bf2f(h.z));
  h.w = f2bf(a3); l.w = f2bf(a3 - bf2f(h.w));
  size_t o = (size_t)mat * 65536 + (n0 + nl) * 256 + k0 + kq * 4;
  *(ushort4*)&Whi[o] = h;
  *(ushort4*)&Wlo[o] = l;
}

// ---------------- merged GEMM (N,256)@(256,768) + fused el/er + bf16 feat ----------------
// 128x128 tile, grid (ceil(M/128), 6). Split-bf16 3-MFMA fp32-grade GEMM.
// Epilogue: wave's 64 cols = head-chunk hw = 2*by + wc (rel=hw>>2, head=hw&3)
// -> 16-lane shuffle reduce -> el/er stores; feat -> bf16 via LDS transpose.

#define LDT 136   // transpose row stride (ushorts); 272B keeps 16B alignment

__global__ __launch_bounds__(256, 2) void gemm_mfma_kernel(
    const float* __restrict__ A, const unsigned short* __restrict__ Bhi,
    const unsigned short* __restrict__ Blo, const float* __restrict__ alf,
    const float* __restrict__ arf, unsigned short* __restrict__ Cb,
    float* __restrict__ el, float* __restrict__ er, int M) {
  __shared__ __align__(16) unsigned short lds[128 * LDT];  // 34816 B >= 32768 B
  unsigned short* As_h = lds;
  unsigned short* As_l = lds + 128 * 32;
  unsigned short* Bs_h = lds + 2 * 128 * 32;
  unsigned short* Bs_l = lds + 3 * 128 * 32;

  const int tid = threadIdx.x;
  const int wave = tid >> 6, lane = tid & 63;
  const int quad = lane >> 4, l16 = lane & 15;
  const int wr = wave & 1, wc = wave >> 1;
  const int m0 = blockIdx.x * 128, n0 = blockIdx.y * 128;

  f32x4 acc[4][4];
#pragma unroll
  for (int i = 0; i < 4; i++)
#pragma unroll
    for (int j = 0; j < 4; j++) acc[i][j] = (f32x4){0.f, 0.f, 0.f, 0.f};

  for (int kb = 0; kb < 8; kb++) {
    int k0 = kb * 32;
#pragma unroll
    for (int j = 0; j < 4; j++) {
      int f = tid + 256 * j;
      int rr = f >> 3, kk = (f & 7) << 2;
      int gm = m0 + rr;
      float4 v = make_float4(0.f, 0.f, 0.f, 0.f);
      if (gm < M) v = *(const float4*)&A[(size_t)gm * 256 + k0 + kk];
      ushort4 h, l;
      h.x = f2bf(v.x); l.x = f2bf(v.x - bf2f(h.x));
      h.y = f2bf(v.y); l.y = f2bf(v.y - bf2f(h.y));
      h.z = f2bf(v.z); l.z = f2bf(v.z - bf2f(h.z));
      h.w = f2bf(v.w); l.w = f2bf(v.w - bf2f(h.w));
      *(ushort4*)&As_h[rr * 32 + kk] = h;
      *(ushort4*)&As_l[rr * 32 + kk] = l;
    }
#pragma unroll
    for (int j = 0; j < 2; j++) {
      int f = tid + 256 * j;
      int rr = f >> 2, kc = (f & 3) << 3;
      size_t go = (size_t)(n0 + rr) * 256 + k0 + kc;   // merged col-major-by-row layout
      *(uint4*)&Bs_h[rr * 32 + kc] = *(const uint4*)&Bhi[go];
      *(uint4*)&Bs_l[rr * 32 + kc] = *(const uint4*)&Blo[go];
    }
    __syncthreads();

    bf16x8 ah[4], al_[4], bh[4], bl[4];
#pragma unroll
    for (int t = 0; t < 4; t++) {
      int arow = (wr * 64 + t * 16 + l16) * 32 + quad * 8;
      int brow = (wc * 64 + t * 16 + l16) * 32 + quad * 8;
      ah[t] = *(const bf16x8*)&As_h[arow];
      al_[t] = *(const bf16x8*)&As_l[arow];
      bh[t] = *(const bf16x8*)&Bs_h[brow];
      bl[t] = *(const bf16x8*)&Bs_l[brow];
    }
#pragma unroll
    for (int mi = 0; mi < 4; mi++)
#pragma unroll
      for (int ni = 0; ni < 4; ni++) {
        acc[mi][ni] = __builtin_amdgcn_mfma_f32_16x16x32_bf16(ah[mi], bl[ni], acc[mi][ni], 0, 0, 0);
        acc[mi][ni] = __builtin_amdgcn_mfma_f32_16x16x32_bf16(al_[mi], bh[ni], acc[mi][ni], 0, 0, 0);
        acc[mi][ni] = __builtin_amdgcn_mfma_f32_16x16x32_bf16(ah[mi], bh[ni], acc[mi][ni], 0, 0, 0);
      }
    __syncthreads();
  }

  // ---- fused el/er: head-chunk hw = 2*by + wc; rel = hw>>2, head = hw&3 ----
  const int hw = (n0 >> 6) + wc;
  const int rel = hw >> 2, hh = hw & 3;
  float alw[4], arw[4];
#pragma unroll
  for (int ni = 0; ni < 4; ni++) {
    int gc = n0 + wc * 64 + ni * 16 + l16;
    alw[ni] = alf[gc]; arw[ni] = arf[gc];
  }
  float pel[4][4], per_[4][4];
#pragma unroll
  for (int mi = 0; mi < 4; mi++)
#pragma unroll
    for (int r = 0; r < 4; r++) {
      float se = 0.f, sr = 0.f;
#pragma unroll
      for (int ni = 0; ni < 4; ni++) {
        se += acc[mi][ni][r] * alw[ni];
        sr += acc[mi][ni][r] * arw[ni];
      }
      pel[mi][r] = se; per_[mi][r] = sr;
    }
#pragma unroll
  for (int off = 1; off < 16; off <<= 1)
#pragma unroll
    for (int mi = 0; mi < 4; mi++)
#pragma unroll
      for (int r = 0; r < 4; r++) {
        pel[mi][r] += __shfl_xor(pel[mi][r], off);
        per_[mi][r] += __shfl_xor(per_[mi][r], off);
      }
  if (l16 == 0) {
#pragma unroll
    for (int mi = 0; mi < 4; mi++)
#pragma unroll
      for (int r = 0; r < 4; r++) {
        int gm = m0 + wr * 64 + mi * 16 + quad * 4 + r;
        if (gm < M) {
          size_t o = ((size_t)rel * N_NODES + gm) * 4 + hh;  // [rel][n][4]
          el[o] = pel[mi][r];
          er[o] = per_[mi][r];
        }
      }
  }

  // ---- feat -> bf16 via LDS transpose, coalesced store (row stride 768) ----
#pragma unroll
  for (int mi = 0; mi < 4; mi++) {
    int row = wr * 64 + mi * 16 + quad * 4;
#pragma unroll
    for (int ni = 0; ni < 4; ni++) {
      int c = wc * 64 + ni * 16 + l16;
#pragma unroll
      for (int r = 0; r < 4; r++)
        lds[(row + r) * LDT + c] = f2bf(acc[mi][ni][r]);
    }
  }
  __syncthreads();
#pragma unroll
  for (int it = 0; it < 8; it++) {
    int chunk = tid + 256 * it;           // 0..2047
    int row = chunk >> 4, c8 = (chunk & 15) * 8;
    int gm = m0 + row;
    if (gm < M)
      *(uint4*)&Cb[(size_t)gm * 768 + n0 + c8] = *(const uint4*)&lds[row * LDT + c8];
  }
}

// ---------------- fused 3-relation aggregation + (final) head mean ----------------

__global__ void agg_kernel(const unsigned short* __restrict__ featb,
                           const float* __restrict__ el, const float* __restrict__ er,
                           const int* __restrict__ row_ptr, const int* __restrict__ col,
                           const float* __restrict__ bias,
                           float* __restrict__ outp, int final_layer) {
  int n = blockIdx.x * 4 + (threadIdx.x >> 6);
  int lane = threadIdx.x & 63;
  if (n >= N_NODES) return;
  const float third = 1.0f / 3.0f;
  float os0 = 0.f, os1 = 0.f, os2 = 0.f, os3 = 0.f;
#pragma unroll
  for (int r = 0; r < N_REL; r++) {
    float4 ern = ((const float4*)er)[(size_t)r * N_NODES + n];
    int s0 = row_ptr[r * RP_STRIDE + n], s1 = row_ptr[r * RP_STRIDE + n + 1];
    const int* cp = col + (size_t)r * N_EDGES;
    float l0 = 0.f, l1 = 0.f, l2 = 0.f, l3 = 0.f;
    float a0 = 0.f, a1 = 0.f, a2 = 0.f, a3 = 0.f;
    for (int i = s0; i < s1; i++) {
      int s = cp[i];
      float4 els = ((const float4*)el)[(size_t)r * N_NODES + s];
      float e0 = els.x + ern.x; e0 = e0 > 0.f ? e0 : NEG_SLOPE * e0;
      float e1 = els.y + ern.y; e1 = e1 > 0.f ? e1 : NEG_SLOPE * e1;
      float e2 = els.z + ern.z; e2 = e2 > 0.f ? e2 : NEG_SLOPE * e2;
      float e3 = els.w + ern.w; e3 = e3 > 0.f ? e3 : NEG_SLOPE * e3;
      // softmax shift-invariant; logits O(few) -> plain exp equivalent
      float p0 = __expf(e0), p1 = __expf(e1), p2 = __expf(e2), p3 = __expf(e3);
      const unsigned short* fs = featb + (size_t)s * 768 + r * 256 + lane;
      a0 += p0 * bf2f(fs[0]);   l0 += p0;
      a1 += p1 * bf2f(fs[64]);  l1 += p1;
      a2 += p2 * bf2f(fs[128]); l2 += p2;
      a3 += p3 * bf2f(fs[192]); l3 += p3;
    }
    float o0 = a0 / fmaxf(l0, 1e-30f) + bias[r * 256 + 0 * 64 + lane];
    float o1 = a1 / fmaxf(l1, 1e-30f) + bias[r * 256 + 1 * 64 + lane];
    float o2 = a2 / fmaxf(l2, 1e-30f) + bias[r * 256 + 2 * 64 + lane];
    float o3 = a3 / fmaxf(l3, 1e-30f) + bias[r * 256 + 3 * 64 + lane];
    o0 = o0 > 0.f ? o0 : __expf(o0) - 1.0f;  // elu
    o1 = o1 > 0.f ? o1 : __expf(o1) - 1.0f;
    o2 = o2 > 0.f ? o2 : __expf(o2) - 1.0f;
    o3 = o3 > 0.f ? o3 : __expf(o3) - 1.0f;
    os0 += o0 * third; os1 += o1 * third; os2 += o2 * third; os3 += o3 * third;
  }
  if (final_layer) {
    outp[(size_t)n * 64 + lane] = 0.25f * (os0 + os1 + os2 + os3);
  } else {
    float* hp = outp + (size_t)n * 256 + lane;
    hp[0] = os0; hp[64] = os1; hp[128] = os2; hp[192] = os3;
  }
}

// ---------------- launch ----------------

extern "C" void kernel_launch(void* const* d_in, const int* in_sizes, int n_in,
                              void* d_out, int out_size, void* d_ws, size_t ws_size,
                              hipStream_t stream) {
  (void)in_sizes; (void)n_in; (void)out_size; (void)ws_size;
  const float* x = (const float*)d_in[0];
  const int* src = (const int*)d_in[1];
  const int* dst = (const int*)d_in[2];
  const float* Wl[3]  = {(const float*)d_in[3], (const float*)d_in[7], (const float*)d_in[11]};
  const float* alL[3] = {(const float*)d_in[4], (const float*)d_in[8], (const float*)d_in[12]};
  const float* arL[3] = {(const float*)d_in[5], (const float*)d_in[9], (const float*)d_in[13]};
  const float* bL[3]  = {(const float*)d_in[6], (const float*)d_in[10], (const float*)d_in[14]};

  char* p = (char*)d_ws;
  auto alloc = [&](size_t bytes) {
    char* q = p;
    p += (bytes + 255) & ~size_t(255);
    return q;
  };
  float* hbuf    = (float*)alloc((size_t)N_NODES * 256 * 4);
  unsigned short* featb = (unsigned short*)alloc((size_t)N_NODES * 768 * 2);
  float* el      = (float*)alloc((size_t)N_REL * N_NODES * 4 * 4);
  float* er      = (float*)alloc((size_t)N_REL * N_NODES * 4 * 4);
  int*   cnt     = (int*)alloc((size_t)N_REL * N_NODES * 4);
  int*   cursor  = (int*)alloc((size_t)N_REL * N_NODES * 4);
  int*   row_ptr = (int*)alloc((size_t)N_REL * RP_STRIDE * 4 + 64);
  int*   col     = (int*)alloc((size_t)N_REL * N_EDGES * 4);
  int*   psum    = (int*)alloc((size_t)N_REL * SCAN_BLOCKS * 4);
  unsigned short* Whi = (unsigned short*)alloc((size_t)9 * 65536 * 2);
  unsigned short* Wlo = (unsigned short*)alloc((size_t)9 * 65536 * 2);

  hipMemsetAsync(cnt, 0, (size_t)N_REL * N_NODES * 4, stream);
  const int totalE = N_REL * N_EDGES;
  count_kernel<<<(totalE + 255) / 256, 256, 0, stream>>>(dst, cnt, totalE);
  block_reduce_kernel<<<N_REL * SCAN_BLOCKS, 256, 0, stream>>>(cnt, psum);
  psum_scan_kernel<<<N_REL, 64, 0, stream>>>(psum, row_ptr);
  scan_write_kernel<<<N_REL * SCAN_BLOCKS, 256, 0, stream>>>(cnt, psum, row_ptr, cursor);
  scatter_kernel<<<(totalE + 255) / 256, 256, 0, stream>>>(src, dst, cursor, col, totalE);
  wsplit_kernel<<<9 * 64, 256, 0, stream>>>(Wl[0], Wl[1], Wl[2], Whi, Wlo);

  const float* hin = x;
  for (int l = 0; l < 3; l++) {
    gemm_mfma_kernel<<<dim3((N_NODES + 127) / 128, 6), 256, 0, stream>>>(
        hin, Whi + (size_t)l * 3 * 65536, Wlo + (size_t)l * 3 * 65536,
        alL[l], arL[l], featb, el, er, N_NODES);
    agg_kernel<<<(N_NODES + 3) / 4, 256, 0, stream>>>(
        featb, el, er, row_ptr, col, bL[l],
        (l == 2) ? (float*)d_out : hbuf, l == 2);
    hin = hbuf;
  }
}

// Round 6
// 1022.008 us; speedup vs baseline: 2.1448x; 1.0157x over previous
//
#include <hip/hip_runtime.h>
#include <hip/hip_bf16.h>

#define N_NODES 50000
#define N_EDGES 400000
#define N_REL   3
#define NEG_SLOPE 0.2f
#define RP_STRIDE 50016           // row_ptr per-relation stride, 16B-aligned for int4
#define SCAN_BLOCKS 49            // ceil(50000/1024)

typedef __bf16 bf16x8 __attribute__((ext_vector_type(8)));
typedef float  f32x4  __attribute__((ext_vector_type(4)));

static __device__ __forceinline__ float bf2f(unsigned short u) {
  return __uint_as_float(((unsigned)u) << 16);
}
static __device__ __forceinline__ unsigned short f2bf(float f) {
  union { float f; unsigned u; } x; x.f = f;
  unsigned r = x.u + 0x7FFFu + ((x.u >> 16) & 1u);   // RNE (finite inputs)
  return (unsigned short)(r >> 16);
}

// ---------------- CSR build ----------------

__global__ void count_kernel(const int* __restrict__ dst, int* __restrict__ cnt, int total) {
  int i = blockIdx.x * 256 + threadIdx.x;
  if (i < total) {
    int r = i / N_EDGES;
    atomicAdd(&cnt[r * N_NODES + dst[i]], 1);
  }
}

__global__ void block_reduce_kernel(const int* __restrict__ cnt, int* __restrict__ psum) {
  __shared__ int s[256];
  int r = blockIdx.x / SCAN_BLOCKS, b = blockIdx.x % SCAN_BLOCKS;
  int node = b * 1024 + threadIdx.x * 4;
  int sum = 0;
  if (node + 3 < N_NODES) {
    int4 v = *(const int4*)&cnt[r * N_NODES + node];
    sum = v.x + v.y + v.z + v.w;
  } else {
    for (int j = 0; j < 4; j++)
      if (node + j < N_NODES) sum += cnt[r * N_NODES + node + j];
  }
  s[threadIdx.x] = sum;
  __syncthreads();
  for (int o = 128; o > 0; o >>= 1) {
    if (threadIdx.x < o) s[threadIdx.x] += s[threadIdx.x + o];
    __syncthreads();
  }
  if (threadIdx.x == 0) psum[r * SCAN_BLOCKS + b] = s[0];
}

__global__ void psum_scan_kernel(int* __restrict__ psum, int* __restrict__ row_ptr) {
  int r = blockIdx.x, t = threadIdx.x;
  int v = (t < SCAN_BLOCKS) ? psum[r * SCAN_BLOCKS + t] : 0;
  int incl = v;
#pragma unroll
  for (int o = 1; o < 64; o <<= 1) {
    int u = __shfl_up(incl, o);
    if (t >= o) incl += u;
  }
  if (t < SCAN_BLOCKS) psum[r * SCAN_BLOCKS + t] = incl - v;
  if (t == SCAN_BLOCKS - 1) row_ptr[r * RP_STRIDE + N_NODES] = incl;
}

__global__ void scan_write_kernel(const int* __restrict__ cnt, const int* __restrict__ psum,
                                  int* __restrict__ row_ptr, int* __restrict__ cursor) {
  __shared__ int s[256];
  int r = blockIdx.x / SCAN_BLOCKS, b = blockIdx.x % SCAN_BLOCKS;
  int tid = threadIdx.x;
  int node = b * 1024 + tid * 4;
  int c[4] = {0, 0, 0, 0};
  if (node + 3 < N_NODES) {
    int4 v = *(const int4*)&cnt[r * N_NODES + node];
    c[0] = v.x; c[1] = v.y; c[2] = v.z; c[3] = v.w;
  } else {
    for (int j = 0; j < 4; j++)
      if (node + j < N_NODES) c[j] = cnt[r * N_NODES + node + j];
  }
  int tsum = c[0] + c[1] + c[2] + c[3];
  s[tid] = tsum;
  __syncthreads();
  for (int o = 1; o < 256; o <<= 1) {
    int v = (tid >= o) ? s[tid - o] : 0;
    __syncthreads();
    s[tid] += v;
    __syncthreads();
  }
  int run = s[tid] - tsum + psum[r * SCAN_BLOCKS + b];
  if (node + 3 < N_NODES) {
    int4 rp = make_int4(run, run + c[0], run + c[0] + c[1], run + c[0] + c[1] + c[2]);
    *(int4*)&row_ptr[r * RP_STRIDE + node] = rp;
    *(int4*)&cursor[r * N_NODES + node] = rp;
  } else {
    for (int j = 0; j < 4; j++) {
      if (node + j < N_NODES) {
        row_ptr[r * RP_STRIDE + node + j] = run;
        cursor[r * N_NODES + node + j] = run;
      }
      run += c[j];
    }
  }
}

__global__ void scatter_kernel(const int* __restrict__ src, const int* __restrict__ dst,
                               int* __restrict__ cursor, int* __restrict__ col, int total) {
  int i = blockIdx.x * 256 + threadIdx.x;
  if (i < total) {
    int r = i / N_EDGES;
    int d = dst[i];
    int pos = atomicAdd(&cursor[r * N_NODES + d], 1);
    col[r * N_EDGES + pos] = src[i];
  }
}

// ---------------- weight transpose + hi/lo bf16 split ----------------
// output layout: [mat=l*3+r][n 0..255][k 0..255] == per-layer merged [col 0..767][k]

__global__ void wsplit_kernel(const float* __restrict__ W0, const float* __restrict__ W1,
                              const float* __restrict__ W2,
                              unsigned short* __restrict__ Whi, unsigned short* __restrict__ Wlo) {
  __shared__ float tile[32][33];
  int mat = blockIdx.x >> 6;           // 0..8
  int t = blockIdx.x & 63;
  int k0 = (t >> 3) * 32, n0 = (t & 7) * 32;
  const float* W = (mat < 3 ? W0 : (mat < 6 ? W1 : W2)) + (size_t)(mat % 3) * 65536;
  int row = threadIdx.x >> 3;          // 0..31 (k)
  int c4 = threadIdx.x & 7;            // 0..7
  float4 v = *(const float4*)&W[(k0 + row) * 256 + n0 + c4 * 4];
  tile[c4 * 4 + 0][row] = v.x;
  tile[c4 * 4 + 1][row] = v.y;
  tile[c4 * 4 + 2][row] = v.z;
  tile[c4 * 4 + 3][row] = v.w;
  __syncthreads();
  int nl = threadIdx.x >> 3;           // 0..31 (n)
  int kq = threadIdx.x & 7;
  ushort4 h, l;
  float a0 = tile[nl][kq * 4 + 0], a1 = tile[nl][kq * 4 + 1];
  float a2 = tile[nl][kq * 4 + 2], a3 = tile[nl][kq * 4 + 3];
  h.x = f2bf(a0); l.x = f2bf(a0 - bf2f(h.x));
  h.y = f2bf(a1); l.y = f2bf(a1 - bf2f(h.y));
  h.z = f2bf(a2); l.z = f2bf(a2 - bf2f(h.z));
  h.w = f2bf(a3); l.w = f2bf(a3 - bf2f(h.w));
  size_t o = (size_t)mat * 65536 + (n0 + nl) * 256 + k0 + kq * 4;
  *(ushort4*)&Whi[o] = h;
  *(ushort4*)&Wlo[o] = l;
}

// ---------------- merged GEMM (N,256)@(256,768) + fused el/er + bf16 feat ----------------
// A input either fp32 (layer 0; split in-kernel) or pre-split bf16 hi/lo planes.

#define LDT 136   // transpose row stride (ushorts); 272B keeps 16B alignment

__global__ __launch_bounds__(256, 2) void gemm_mfma_kernel(
    const float* __restrict__ Af, const unsigned short* __restrict__ Ah,
    const unsigned short* __restrict__ Al, const unsigned short* __restrict__ Bhi,
    const unsigned short* __restrict__ Blo, const float* __restrict__ alf,
    const float* __restrict__ arf, unsigned short* __restrict__ Cb,
    float* __restrict__ el, float* __restrict__ er, int M, int use_f32) {
  __shared__ __align__(16) unsigned short lds[128 * LDT];  // 34816 B >= 32768 B
  unsigned short* As_h = lds;
  unsigned short* As_l = lds + 128 * 32;
  unsigned short* Bs_h = lds + 2 * 128 * 32;
  unsigned short* Bs_l = lds + 3 * 128 * 32;

  const int tid = threadIdx.x;
  const int wave = tid >> 6, lane = tid & 63;
  const int quad = lane >> 4, l16 = lane & 15;
  const int wr = wave & 1, wc = wave >> 1;
  const int m0 = blockIdx.x * 128, n0 = blockIdx.y * 128;

  f32x4 acc[4][4];
#pragma unroll
  for (int i = 0; i < 4; i++)
#pragma unroll
    for (int j = 0; j < 4; j++) acc[i][j] = (f32x4){0.f, 0.f, 0.f, 0.f};

  for (int kb = 0; kb < 8; kb++) {
    int k0 = kb * 32;
    if (use_f32) {
#pragma unroll
      for (int j = 0; j < 4; j++) {
        int f = tid + 256 * j;
        int rr = f >> 3, kk = (f & 7) << 2;
        int gm = m0 + rr;
        float4 v = make_float4(0.f, 0.f, 0.f, 0.f);
        if (gm < M) v = *(const float4*)&Af[(size_t)gm * 256 + k0 + kk];
        ushort4 h, l;
        h.x = f2bf(v.x); l.x = f2bf(v.x - bf2f(h.x));
        h.y = f2bf(v.y); l.y = f2bf(v.y - bf2f(h.y));
        h.z = f2bf(v.z); l.z = f2bf(v.z - bf2f(h.z));
        h.w = f2bf(v.w); l.w = f2bf(v.w - bf2f(h.w));
        *(ushort4*)&As_h[rr * 32 + kk] = h;
        *(ushort4*)&As_l[rr * 32 + kk] = l;
      }
    } else {
#pragma unroll
      for (int j = 0; j < 4; j++) {
        int f = tid + 256 * j;
        int rr = f >> 3, kk = (f & 7) << 2;
        int gm = m0 + rr;
        ushort4 h = {0, 0, 0, 0}, l = {0, 0, 0, 0};
        if (gm < M) {
          h = *(const ushort4*)&Ah[(size_t)gm * 256 + k0 + kk];
          l = *(const ushort4*)&Al[(size_t)gm * 256 + k0 + kk];
        }
        *(ushort4*)&As_h[rr * 32 + kk] = h;
        *(ushort4*)&As_l[rr * 32 + kk] = l;
      }
    }
#pragma unroll
    for (int j = 0; j < 2; j++) {
      int f = tid + 256 * j;
      int rr = f >> 2, kc = (f & 3) << 3;
      size_t go = (size_t)(n0 + rr) * 256 + k0 + kc;
      *(uint4*)&Bs_h[rr * 32 + kc] = *(const uint4*)&Bhi[go];
      *(uint4*)&Bs_l[rr * 32 + kc] = *(const uint4*)&Blo[go];
    }
    __syncthreads();

    bf16x8 ah[4], al_[4], bh[4], bl[4];
#pragma unroll
    for (int t = 0; t < 4; t++) {
      int arow = (wr * 64 + t * 16 + l16) * 32 + quad * 8;
      int brow = (wc * 64 + t * 16 + l16) * 32 + quad * 8;
      ah[t] = *(const bf16x8*)&As_h[arow];
      al_[t] = *(const bf16x8*)&As_l[arow];
      bh[t] = *(const bf16x8*)&Bs_h[brow];
      bl[t] = *(const bf16x8*)&Bs_l[brow];
    }
#pragma unroll
    for (int mi = 0; mi < 4; mi++)
#pragma unroll
      for (int ni = 0; ni < 4; ni++) {
        acc[mi][ni] = __builtin_amdgcn_mfma_f32_16x16x32_bf16(ah[mi], bl[ni], acc[mi][ni], 0, 0, 0);
        acc[mi][ni] = __builtin_amdgcn_mfma_f32_16x16x32_bf16(al_[mi], bh[ni], acc[mi][ni], 0, 0, 0);
        acc[mi][ni] = __builtin_amdgcn_mfma_f32_16x16x32_bf16(ah[mi], bh[ni], acc[mi][ni], 0, 0, 0);
      }
    __syncthreads();
  }

  // ---- fused el/er: head-chunk hw = 2*by + wc; rel = hw>>2, head = hw&3 ----
  const int hw = (n0 >> 6) + wc;
  const int rel = hw >> 2, hh = hw & 3;
  float alw[4], arw[4];
#pragma unroll
  for (int ni = 0; ni < 4; ni++) {
    int gc = n0 + wc * 64 + ni * 16 + l16;
    alw[ni] = alf[gc]; arw[ni] = arf[gc];
  }
  float pel[4][4], per_[4][4];
#pragma unroll
  for (int mi = 0; mi < 4; mi++)
#pragma unroll
    for (int r = 0; r < 4; r++) {
      float se = 0.f, sr = 0.f;
#pragma unroll
      for (int ni = 0; ni < 4; ni++) {
        se += acc[mi][ni][r] * alw[ni];
        sr += acc[mi][ni][r] * arw[ni];
      }
      pel[mi][r] = se; per_[mi][r] = sr;
    }
#pragma unroll
  for (int off = 1; off < 16; off <<= 1)
#pragma unroll
    for (int mi = 0; mi < 4; mi++)
#pragma unroll
      for (int r = 0; r < 4; r++) {
        pel[mi][r] += __shfl_xor(pel[mi][r], off);
        per_[mi][r] += __shfl_xor(per_[mi][r], off);
      }
  if (l16 == 0) {
#pragma unroll
    for (int mi = 0; mi < 4; mi++)
#pragma unroll
      for (int r = 0; r < 4; r++) {
        int gm = m0 + wr * 64 + mi * 16 + quad * 4 + r;
        if (gm < M) {
          size_t o = ((size_t)rel * N_NODES + gm) * 4 + hh;  // [rel][n][4]
          el[o] = pel[mi][r];
          er[o] = per_[mi][r];
        }
      }
  }

  // ---- feat -> bf16 via LDS transpose, coalesced store (row stride 768) ----
#pragma unroll
  for (int mi = 0; mi < 4; mi++) {
    int row = wr * 64 + mi * 16 + quad * 4;
#pragma unroll
    for (int ni = 0; ni < 4; ni++) {
      int c = wc * 64 + ni * 16 + l16;
#pragma unroll
      for (int r = 0; r < 4; r++)
        lds[(row + r) * LDT + c] = f2bf(acc[mi][ni][r]);
    }
  }
  __syncthreads();
#pragma unroll
  for (int it = 0; it < 8; it++) {
    int chunk = tid + 256 * it;           // 0..2047
    int row = chunk >> 4, c8 = (chunk & 15) * 8;
    int gm = m0 + row;
    if (gm < M)
      *(uint4*)&Cb[(size_t)gm * 768 + n0 + c8] = *(const uint4*)&lds[row * LDT + c8];
  }
}

// ---------------- alpha: normalized softmax weight per CSR slot ----------------
// One wave per node; lanes parallel over edges. alpha[r][slot][4] fp32.

__global__ void alpha_kernel(const float* __restrict__ el, const float* __restrict__ er,
                             const int* __restrict__ row_ptr, const int* __restrict__ col,
                             float* __restrict__ alpha) {
  int n = blockIdx.x * 4 + (threadIdx.x >> 6);
  int lane = threadIdx.x & 63;
  if (n >= N_NODES) return;
#pragma unroll
  for (int r = 0; r < N_REL; r++) {
    float4 ern = ((const float4*)er)[(size_t)r * N_NODES + n];
    int s0 = row_ptr[r * RP_STRIDE + n], s1 = row_ptr[r * RP_STRIDE + n + 1];
    int deg = s1 - s0;
    if (deg <= 0) continue;
    const int* cp = col + (size_t)r * N_EDGES;
    float4* aout = (float4*)alpha + (size_t)r * N_EDGES;
    if (deg <= 64) {
      int i = s0 + lane;
      float p0 = 0.f, p1 = 0.f, p2 = 0.f, p3 = 0.f;
      if (lane < deg) {
        int s = cp[i];
        float4 els = ((const float4*)el)[(size_t)r * N_NODES + s];
        float e0 = els.x + ern.x; e0 = e0 > 0.f ? e0 : NEG_SLOPE * e0; p0 = __expf(e0);
        float e1 = els.y + ern.y; e1 = e1 > 0.f ? e1 : NEG_SLOPE * e1; p1 = __expf(e1);
        float e2 = els.z + ern.z; e2 = e2 > 0.f ? e2 : NEG_SLOPE * e2; p2 = __expf(e2);
        float e3 = els.w + ern.w; e3 = e3 > 0.f ? e3 : NEG_SLOPE * e3; p3 = __expf(e3);
      }
      float d0 = p0, d1 = p1, d2 = p2, d3 = p3;
#pragma unroll
      for (int o = 1; o < 64; o <<= 1) {
        d0 += __shfl_xor(d0, o); d1 += __shfl_xor(d1, o);
        d2 += __shfl_xor(d2, o); d3 += __shfl_xor(d3, o);
      }
      float i0 = 1.f / fmaxf(d0, 1e-30f), i1 = 1.f / fmaxf(d1, 1e-30f);
      float i2 = 1.f / fmaxf(d2, 1e-30f), i3 = 1.f / fmaxf(d3, 1e-30f);
      if (lane < deg) aout[i] = make_float4(p0 * i0, p1 * i1, p2 * i2, p3 * i3);
    } else {
      float d0 = 0.f, d1 = 0.f, d2 = 0.f, d3 = 0.f;
      for (int base = s0; base < s1; base += 64) {
        int i = base + lane;
        float p0 = 0.f, p1 = 0.f, p2 = 0.f, p3 = 0.f;
        if (i < s1) {
          int s = cp[i];
          float4 els = ((const float4*)el)[(size_t)r * N_NODES + s];
          float e0 = els.x + ern.x; e0 = e0 > 0.f ? e0 : NEG_SLOPE * e0; p0 = __expf(e0);
          float e1 = els.y + ern.y; e1 = e1 > 0.f ? e1 : NEG_SLOPE * e1; p1 = __expf(e1);
          float e2 = els.z + ern.z; e2 = e2 > 0.f ? e2 : NEG_SLOPE * e2; p2 = __expf(e2);
          float e3 = els.w + ern.w; e3 = e3 > 0.f ? e3 : NEG_SLOPE * e3; p3 = __expf(e3);
          aout[i] = make_float4(p0, p1, p2, p3);
        }
        float c0 = p0, c1 = p1, c2 = p2, c3 = p3;
#pragma unroll
        for (int o = 1; o < 64; o <<= 1) {
          c0 += __shfl_xor(c0, o); c1 += __shfl_xor(c1, o);
          c2 += __shfl_xor(c2, o); c3 += __shfl_xor(c3, o);
        }
        d0 += c0; d1 += c1; d2 += c2; d3 += c3;
      }
      float i0 = 1.f / fmaxf(d0, 1e-30f), i1 = 1.f / fmaxf(d1, 1e-30f);
      float i2 = 1.f / fmaxf(d2, 1e-30f), i3 = 1.f / fmaxf(d3, 1e-30f);
      for (int base = s0; base < s1; base += 64) {
        int i = base + lane;
        if (i < s1) {
          float4 v = aout[i];
          aout[i] = make_float4(v.x * i0, v.y * i1, v.z * i2, v.w * i3);
        }
      }
    }
  }
}

// ---------------- aggregation: pure weighted gather-sum ----------------
// Lane L covers feature elements 4L..4L+3 (head = L>>4). Output: pre-split
// bf16 hi/lo planes (layers 0,1) or fp32 head-mean to d_out (layer 2).

__global__ void agg_kernel(const unsigned short* __restrict__ featb,
                           const float* __restrict__ alpha,
                           const int* __restrict__ row_ptr, const int* __restrict__ col,
                           const float* __restrict__ bias,
                           unsigned short* __restrict__ hH, unsigned short* __restrict__ hL,
                           float* __restrict__ outF, int final_layer) {
  int n = blockIdx.x * 4 + (threadIdx.x >> 6);
  int L = threadIdx.x & 63;
  if (n >= N_NODES) return;
  const int hsel = L >> 4;
  const float third = 1.0f / 3.0f;
  float os0 = 0.f, os1 = 0.f, os2 = 0.f, os3 = 0.f;
#pragma unroll
  for (int r = 0; r < N_REL; r++) {
    int s0 = row_ptr[r * RP_STRIDE + n], s1 = row_ptr[r * RP_STRIDE + n + 1];
    const int* cp = col + (size_t)r * N_EDGES;
    const float* ap = alpha + (size_t)r * N_EDGES * 4;
    const unsigned short* fbase = featb + r * 256 + 4 * L;
    float a0 = 0.f, a1 = 0.f, a2 = 0.f, a3 = 0.f;
    int i = s0;
    for (; i + 1 < s1; i += 2) {
      int sA = cp[i], sB = cp[i + 1];
      float wA = ap[(size_t)i * 4 + hsel];
      float wB = ap[(size_t)(i + 1) * 4 + hsel];
      ushort4 fA = *(const ushort4*)&fbase[(size_t)sA * 768];
      ushort4 fB = *(const ushort4*)&fbase[(size_t)sB * 768];
      a0 += wA * bf2f(fA.x) + wB * bf2f(fB.x);
      a1 += wA * bf2f(fA.y) + wB * bf2f(fB.y);
      a2 += wA * bf2f(fA.z) + wB * bf2f(fB.z);
      a3 += wA * bf2f(fA.w) + wB * bf2f(fB.w);
    }
    if (i < s1) {
      int sA = cp[i];
      float wA = ap[(size_t)i * 4 + hsel];
      ushort4 fA = *(const ushort4*)&fbase[(size_t)sA * 768];
      a0 += wA * bf2f(fA.x); a1 += wA * bf2f(fA.y);
      a2 += wA * bf2f(fA.z); a3 += wA * bf2f(fA.w);
    }
    float4 bv = *(const float4*)&bias[r * 256 + 4 * L];
    float o0 = a0 + bv.x, o1 = a1 + bv.y, o2 = a2 + bv.z, o3 = a3 + bv.w;
    o0 = o0 > 0.f ? o0 : __expf(o0) - 1.0f;  // elu
    o1 = o1 > 0.f ? o1 : __expf(o1) - 1.0f;
    o2 = o2 > 0.f ? o2 : __expf(o2) - 1.0f;
    o3 = o3 > 0.f ? o3 : __expf(o3) - 1.0f;
    os0 += o0 * third; os1 += o1 * third; os2 += o2 * third; os3 += o3 * third;
  }
  if (final_layer) {
    // head mean: sum lanes differing in bits 4,5 (heads), same d-range
#pragma unroll
    for (int o = 16; o <= 32; o <<= 1) {
      os0 += __shfl_xor(os0, o); os1 += __shfl_xor(os1, o);
      os2 += __shfl_xor(os2, o); os3 += __shfl_xor(os3, o);
    }
    if (L < 16)
      *(float4*)&outF[(size_t)n * 64 + L * 4] =
          make_float4(0.25f * os0, 0.25f * os1, 0.25f * os2, 0.25f * os3);
  } else {
    ushort4 h, l;
    h.x = f2bf(os0); l.x = f2bf(os0 - bf2f(h.x));
    h.y = f2bf(os1); l.y = f2bf(os1 - bf2f(h.y));
    h.z = f2bf(os2); l.z = f2bf(os2 - bf2f(h.z));
    h.w = f2bf(os3); l.w = f2bf(os3 - bf2f(h.w));
    *(ushort4*)&hH[(size_t)n * 256 + 4 * L] = h;
    *(ushort4*)&hL[(size_t)n * 256 + 4 * L] = l;
  }
}

// ---------------- launch ----------------

extern "C" void kernel_launch(void* const* d_in, const int* in_sizes, int n_in,
                              void* d_out, int out_size, void* d_ws, size_t ws_size,
                              hipStream_t stream) {
  (void)in_sizes; (void)n_in; (void)out_size; (void)ws_size;
  const float* x = (const float*)d_in[0];
  const int* src = (const int*)d_in[1];
  const int* dst = (const int*)d_in[2];
  const float* Wl[3]  = {(const float*)d_in[3], (const float*)d_in[7], (const float*)d_in[11]};
  const float* alL[3] = {(const float*)d_in[4], (const float*)d_in[8], (const float*)d_in[12]};
  const float* arL[3] = {(const float*)d_in[5], (const float*)d_in[9], (const float*)d_in[13]};
  const float* bL[3]  = {(const float*)d_in[6], (const float*)d_in[10], (const float*)d_in[14]};

  char* p = (char*)d_ws;
  auto alloc = [&](size_t bytes) {
    char* q = p;
    p += (bytes + 255) & ~size_t(255);
    return q;
  };
  unsigned short* hH = (unsigned short*)alloc((size_t)N_NODES * 256 * 2);
  unsigned short* hL = (unsigned short*)alloc((size_t)N_NODES * 256 * 2);
  unsigned short* featb = (unsigned short*)alloc((size_t)N_NODES * 768 * 2);
  float* el      = (float*)alloc((size_t)N_REL * N_NODES * 4 * 4);
  float* er      = (float*)alloc((size_t)N_REL * N_NODES * 4 * 4);
  float* alphaw  = (float*)alloc((size_t)N_REL * N_EDGES * 4 * 4);
  int*   cnt     = (int*)alloc((size_t)N_REL * N_NODES * 4);
  int*   cursor  = (int*)alloc((size_t)N_REL * N_NODES * 4);
  int*   row_ptr = (int*)alloc((size_t)N_REL * RP_STRIDE * 4 + 64);
  int*   col     = (int*)alloc((size_t)N_REL * N_EDGES * 4);
  int*   psum    = (int*)alloc((size_t)N_REL * SCAN_BLOCKS * 4);
  unsigned short* Whi = (unsigned short*)alloc((size_t)9 * 65536 * 2);
  unsigned short* Wlo = (unsigned short*)alloc((size_t)9 * 65536 * 2);

  hipMemsetAsync(cnt, 0, (size_t)N_REL * N_NODES * 4, stream);
  const int totalE = N_REL * N_EDGES;
  count_kernel<<<(totalE + 255) / 256, 256, 0, stream>>>(dst, cnt, totalE);
  block_reduce_kernel<<<N_REL * SCAN_BLOCKS, 256, 0, stream>>>(cnt, psum);
  psum_scan_kernel<<<N_REL, 64, 0, stream>>>(psum, row_ptr);
  scan_write_kernel<<<N_REL * SCAN_BLOCKS, 256, 0, stream>>>(cnt, psum, row_ptr, cursor);
  scatter_kernel<<<(totalE + 255) / 256, 256, 0, stream>>>(src, dst, cursor, col, totalE);
  wsplit_kernel<<<9 * 64, 256, 0, stream>>>(Wl[0], Wl[1], Wl[2], Whi, Wlo);

  const int nodeBlocks = (N_NODES + 3) / 4;
  for (int l = 0; l < 3; l++) {
    gemm_mfma_kernel<<<dim3((N_NODES + 127) / 128, 6), 256, 0, stream>>>(
        x, hH, hL, Whi + (size_t)l * 3 * 65536, Wlo + (size_t)l * 3 * 65536,
        alL[l], arL[l], featb, el, er, N_NODES, l == 0);
    alpha_kernel<<<nodeBlocks, 256, 0, stream>>>(el, er, row_ptr, col, alphaw);
    agg_kernel<<<nodeBlocks, 256, 0, stream>>>(
        featb, alphaw, row_ptr, col, bL[l], hH, hL, (float*)d_out, l == 2);
  }
}

// Round 7
// 1021.895 us; speedup vs baseline: 2.1450x; 1.0001x over previous
//
#include <hip/hip_runtime.h>
#include <hip/hip_bf16.h>

#define N_NODES 50000
#define N_EDGES 400000
#define N_REL   3
#define NEG_SLOPE 0.2f
#define RP_STRIDE 50016           // row_ptr per-relation stride, 16B-aligned for int4
#define SCAN_BLOCKS 49            // ceil(50000/1024)

typedef __bf16 bf16x8 __attribute__((ext_vector_type(8)));
typedef float  f32x4  __attribute__((ext_vector_type(4)));

static __device__ __forceinline__ float bf2f(unsigned short u) {
  return __uint_as_float(((unsigned)u) << 16);
}
static __device__ __forceinline__ unsigned short f2bf(float f) {
  union { float f; unsigned u; } x; x.f = f;
  unsigned r = x.u + 0x7FFFu + ((x.u >> 16) & 1u);   // RNE (finite inputs)
  return (unsigned short)(r >> 16);
}

// ---------------- CSR build ----------------

__global__ void count_kernel(const int* __restrict__ dst, int* __restrict__ cnt, int total) {
  int i = blockIdx.x * 256 + threadIdx.x;
  if (i < total) {
    int r = i / N_EDGES;
    atomicAdd(&cnt[r * N_NODES + dst[i]], 1);
  }
}

__global__ void block_reduce_kernel(const int* __restrict__ cnt, int* __restrict__ psum) {
  __shared__ int s[256];
  int r = blockIdx.x / SCAN_BLOCKS, b = blockIdx.x % SCAN_BLOCKS;
  int node = b * 1024 + threadIdx.x * 4;
  int sum = 0;
  if (node + 3 < N_NODES) {
    int4 v = *(const int4*)&cnt[r * N_NODES + node];
    sum = v.x + v.y + v.z + v.w;
  } else {
    for (int j = 0; j < 4; j++)
      if (node + j < N_NODES) sum += cnt[r * N_NODES + node + j];
  }
  s[threadIdx.x] = sum;
  __syncthreads();
  for (int o = 128; o > 0; o >>= 1) {
    if (threadIdx.x < o) s[threadIdx.x] += s[threadIdx.x + o];
    __syncthreads();
  }
  if (threadIdx.x == 0) psum[r * SCAN_BLOCKS + b] = s[0];
}

__global__ void psum_scan_kernel(int* __restrict__ psum, int* __restrict__ row_ptr) {
  int r = blockIdx.x, t = threadIdx.x;
  int v = (t < SCAN_BLOCKS) ? psum[r * SCAN_BLOCKS + t] : 0;
  int incl = v;
#pragma unroll
  for (int o = 1; o < 64; o <<= 1) {
    int u = __shfl_up(incl, o);
    if (t >= o) incl += u;
  }
  if (t < SCAN_BLOCKS) psum[r * SCAN_BLOCKS + t] = incl - v;
  if (t == SCAN_BLOCKS - 1) row_ptr[r * RP_STRIDE + N_NODES] = incl;
}

__global__ void scan_write_kernel(const int* __restrict__ cnt, const int* __restrict__ psum,
                                  int* __restrict__ row_ptr, int* __restrict__ cursor) {
  __shared__ int s[256];
  int r = blockIdx.x / SCAN_BLOCKS, b = blockIdx.x % SCAN_BLOCKS;
  int tid = threadIdx.x;
  int node = b * 1024 + tid * 4;
  int c[4] = {0, 0, 0, 0};
  if (node + 3 < N_NODES) {
    int4 v = *(const int4*)&cnt[r * N_NODES + node];
    c[0] = v.x; c[1] = v.y; c[2] = v.z; c[3] = v.w;
  } else {
    for (int j = 0; j < 4; j++)
      if (node + j < N_NODES) c[j] = cnt[r * N_NODES + node + j];
  }
  int tsum = c[0] + c[1] + c[2] + c[3];
  s[tid] = tsum;
  __syncthreads();
  for (int o = 1; o < 256; o <<= 1) {
    int v = (tid >= o) ? s[tid - o] : 0;
    __syncthreads();
    s[tid] += v;
    __syncthreads();
  }
  int run = s[tid] - tsum + psum[r * SCAN_BLOCKS + b];
  if (node + 3 < N_NODES) {
    int4 rp = make_int4(run, run + c[0], run + c[0] + c[1], run + c[0] + c[1] + c[2]);
    *(int4*)&row_ptr[r * RP_STRIDE + node] = rp;
    *(int4*)&cursor[r * N_NODES + node] = rp;
  } else {
    for (int j = 0; j < 4; j++) {
      if (node + j < N_NODES) {
        row_ptr[r * RP_STRIDE + node + j] = run;
        cursor[r * N_NODES + node + j] = run;
      }
      run += c[j];
    }
  }
}

__global__ void scatter_kernel(const int* __restrict__ src, const int* __restrict__ dst,
                               int* __restrict__ cursor, int* __restrict__ col, int total) {
  int i = blockIdx.x * 256 + threadIdx.x;
  if (i < total) {
    int r = i / N_EDGES;
    int d = dst[i];
    int pos = atomicAdd(&cursor[r * N_NODES + d], 1);
    col[r * N_EDGES + pos] = src[i];
  }
}

// ---------------- weight transpose + hi/lo bf16 split ----------------
// output layout: [mat=l*3+r][n 0..255][k 0..255] == per-layer merged [col 0..767][k]

__global__ void wsplit_kernel(const float* __restrict__ W0, const float* __restrict__ W1,
                              const float* __restrict__ W2,
                              unsigned short* __restrict__ Whi, unsigned short* __restrict__ Wlo) {
  __shared__ float tile[32][33];
  int mat = blockIdx.x >> 6;           // 0..8
  int t = blockIdx.x & 63;
  int k0 = (t >> 3) * 32, n0 = (t & 7) * 32;
  const float* W = (mat < 3 ? W0 : (mat < 6 ? W1 : W2)) + (size_t)(mat % 3) * 65536;
  int row = threadIdx.x >> 3;          // 0..31 (k)
  int c4 = threadIdx.x & 7;            // 0..7
  float4 v = *(const float4*)&W[(k0 + row) * 256 + n0 + c4 * 4];
  tile[c4 * 4 + 0][row] = v.x;
  tile[c4 * 4 + 1][row] = v.y;
  tile[c4 * 4 + 2][row] = v.z;
  tile[c4 * 4 + 3][row] = v.w;
  __syncthreads();
  int nl = threadIdx.x >> 3;           // 0..31 (n)
  int kq = threadIdx.x & 7;
  ushort4 h, l;
  float a0 = tile[nl][kq * 4 + 0], a1 = tile[nl][kq * 4 + 1];
  float a2 = tile[nl][kq * 4 + 2], a3 = tile[nl][kq * 4 + 3];
  h.x = f2bf(a0); l.x = f2bf(a0 - bf2f(h.x));
  h.y = f2bf(a1); l.y = f2bf(a1 - bf2f(h.y));
  h.z = f2bf(a2); l.z = f2bf(a2 - bf2f(h.z));
  h.w = f2bf(a3); l.w = f2bf(a3 - bf2f(h.w));
  size_t o = (size_t)mat * 65536 + (n0 + nl) * 256 + k0 + kq * 4;
  *(ushort4*)&Whi[o] = h;
  *(ushort4*)&Wlo[o] = l;
}

// ---------------- merged GEMM (N,256)@(256,768) + fused el/er + bf16 feat ----------------
// Grid (6, ceil(M/128)): consecutive blocks share the A-row tile (L3-hot).
// LDS fragment rows padded to 40 ushorts (80B): row->bank start (row*20)%32
// covers 8 distinct offsets -> max 2-way conflict (free).

#define LDS_S 40  // staging row stride in ushorts
#define LDT  136  // transpose row stride (ushorts); 272B keeps 16B alignment

__global__ __launch_bounds__(256, 2) void gemm_mfma_kernel(
    const float* __restrict__ Af, const unsigned short* __restrict__ Ah,
    const unsigned short* __restrict__ Al, const unsigned short* __restrict__ Bhi,
    const unsigned short* __restrict__ Blo, const float* __restrict__ alf,
    const float* __restrict__ arf, unsigned short* __restrict__ Cb,
    float* __restrict__ el, float* __restrict__ er, int M, int use_f32) {
  __shared__ __align__(16) unsigned short lds[4 * 128 * LDS_S];  // 40960 B
  unsigned short* As_h = lds;
  unsigned short* As_l = lds + 128 * LDS_S;
  unsigned short* Bs_h = lds + 2 * 128 * LDS_S;
  unsigned short* Bs_l = lds + 3 * 128 * LDS_S;

  const int tid = threadIdx.x;
  const int wave = tid >> 6, lane = tid & 63;
  const int quad = lane >> 4, l16 = lane & 15;
  const int wr = wave & 1, wc = wave >> 1;
  const int m0 = blockIdx.y * 128, n0 = blockIdx.x * 128;

  f32x4 acc[4][4];
#pragma unroll
  for (int i = 0; i < 4; i++)
#pragma unroll
    for (int j = 0; j < 4; j++) acc[i][j] = (f32x4){0.f, 0.f, 0.f, 0.f};

  for (int kb = 0; kb < 8; kb++) {
    int k0 = kb * 32;
    if (use_f32) {
#pragma unroll
      for (int j = 0; j < 4; j++) {
        int f = tid + 256 * j;
        int rr = f >> 3, kk = (f & 7) << 2;
        int gm = m0 + rr;
        float4 v = make_float4(0.f, 0.f, 0.f, 0.f);
        if (gm < M) v = *(const float4*)&Af[(size_t)gm * 256 + k0 + kk];
        ushort4 h, l;
        h.x = f2bf(v.x); l.x = f2bf(v.x - bf2f(h.x));
        h.y = f2bf(v.y); l.y = f2bf(v.y - bf2f(h.y));
        h.z = f2bf(v.z); l.z = f2bf(v.z - bf2f(h.z));
        h.w = f2bf(v.w); l.w = f2bf(v.w - bf2f(h.w));
        *(ushort4*)&As_h[rr * LDS_S + kk] = h;
        *(ushort4*)&As_l[rr * LDS_S + kk] = l;
      }
    } else {
#pragma unroll
      for (int j = 0; j < 4; j++) {
        int f = tid + 256 * j;
        int rr = f >> 3, kk = (f & 7) << 2;
        int gm = m0 + rr;
        ushort4 h = {0, 0, 0, 0}, l = {0, 0, 0, 0};
        if (gm < M) {
          h = *(const ushort4*)&Ah[(size_t)gm * 256 + k0 + kk];
          l = *(const ushort4*)&Al[(size_t)gm * 256 + k0 + kk];
        }
        *(ushort4*)&As_h[rr * LDS_S + kk] = h;
        *(ushort4*)&As_l[rr * LDS_S + kk] = l;
      }
    }
#pragma unroll
    for (int j = 0; j < 2; j++) {
      int f = tid + 256 * j;
      int rr = f >> 2, kc = (f & 3) << 3;
      size_t go = (size_t)(n0 + rr) * 256 + k0 + kc;
      *(uint4*)&Bs_h[rr * LDS_S + kc] = *(const uint4*)&Bhi[go];
      *(uint4*)&Bs_l[rr * LDS_S + kc] = *(const uint4*)&Blo[go];
    }
    __syncthreads();

    bf16x8 ah[4], al_[4], bh[4], bl[4];
#pragma unroll
    for (int t = 0; t < 4; t++) {
      int arow = (wr * 64 + t * 16 + l16) * LDS_S + quad * 8;
      int brow = (wc * 64 + t * 16 + l16) * LDS_S + quad * 8;
      ah[t] = *(const bf16x8*)&As_h[arow];
      al_[t] = *(const bf16x8*)&As_l[arow];
      bh[t] = *(const bf16x8*)&Bs_h[brow];
      bl[t] = *(const bf16x8*)&Bs_l[brow];
    }
#pragma unroll
    for (int mi = 0; mi < 4; mi++)
#pragma unroll
      for (int ni = 0; ni < 4; ni++) {
        acc[mi][ni] = __builtin_amdgcn_mfma_f32_16x16x32_bf16(ah[mi], bl[ni], acc[mi][ni], 0, 0, 0);
        acc[mi][ni] = __builtin_amdgcn_mfma_f32_16x16x32_bf16(al_[mi], bh[ni], acc[mi][ni], 0, 0, 0);
        acc[mi][ni] = __builtin_amdgcn_mfma_f32_16x16x32_bf16(ah[mi], bh[ni], acc[mi][ni], 0, 0, 0);
      }
    __syncthreads();
  }

  // ---- fused el/er: head-chunk hw = 2*bx + wc; rel = hw>>2, head = hw&3 ----
  const int hw = (n0 >> 6) + wc;
  const int rel = hw >> 2, hh = hw & 3;
  float alw[4], arw[4];
#pragma unroll
  for (int ni = 0; ni < 4; ni++) {
    int gc = n0 + wc * 64 + ni * 16 + l16;
    alw[ni] = alf[gc]; arw[ni] = arf[gc];
  }
  float pel[4][4], per_[4][4];
#pragma unroll
  for (int mi = 0; mi < 4; mi++)
#pragma unroll
    for (int r = 0; r < 4; r++) {
      float se = 0.f, sr = 0.f;
#pragma unroll
      for (int ni = 0; ni < 4; ni++) {
        se += acc[mi][ni][r] * alw[ni];
        sr += acc[mi][ni][r] * arw[ni];
      }
      pel[mi][r] = se; per_[mi][r] = sr;
    }
#pragma unroll
  for (int off = 1; off < 16; off <<= 1)
#pragma unroll
    for (int mi = 0; mi < 4; mi++)
#pragma unroll
      for (int r = 0; r < 4; r++) {
        pel[mi][r] += __shfl_xor(pel[mi][r], off);
        per_[mi][r] += __shfl_xor(per_[mi][r], off);
      }
  if (l16 == 0) {
#pragma unroll
    for (int mi = 0; mi < 4; mi++)
#pragma unroll
      for (int r = 0; r < 4; r++) {
        int gm = m0 + wr * 64 + mi * 16 + quad * 4 + r;
        if (gm < M) {
          size_t o = ((size_t)rel * N_NODES + gm) * 4 + hh;  // [rel][n][4]
          el[o] = pel[mi][r];
          er[o] = per_[mi][r];
        }
      }
  }

  // ---- feat -> bf16 via LDS transpose, coalesced store (row stride 768) ----
#pragma unroll
  for (int mi = 0; mi < 4; mi++) {
    int row = wr * 64 + mi * 16 + quad * 4;
#pragma unroll
    for (int ni = 0; ni < 4; ni++) {
      int c = wc * 64 + ni * 16 + l16;
#pragma unroll
      for (int r = 0; r < 4; r++)
        lds[(row + r) * LDT + c] = f2bf(acc[mi][ni][r]);
    }
  }
  __syncthreads();
#pragma unroll
  for (int it = 0; it < 8; it++) {
    int chunk = tid + 256 * it;           // 0..2047
    int row = chunk >> 4, c8 = (chunk & 15) * 8;
    int gm = m0 + row;
    if (gm < M)
      *(uint4*)&Cb[(size_t)gm * 768 + n0 + c8] = *(const uint4*)&lds[row * LDT + c8];
  }
}

// ---------------- alpha: normalized softmax weight per CSR slot ----------------

__global__ void alpha_kernel(const float* __restrict__ el, const float* __restrict__ er,
                             const int* __restrict__ row_ptr, const int* __restrict__ col,
                             float* __restrict__ alpha) {
  int n = blockIdx.x * 4 + (threadIdx.x >> 6);
  int lane = threadIdx.x & 63;
  if (n >= N_NODES) return;
#pragma unroll
  for (int r = 0; r < N_REL; r++) {
    float4 ern = ((const float4*)er)[(size_t)r * N_NODES + n];
    int s0 = row_ptr[r * RP_STRIDE + n], s1 = row_ptr[r * RP_STRIDE + n + 1];
    int deg = s1 - s0;
    if (deg <= 0) continue;
    const int* cp = col + (size_t)r * N_EDGES;
    float4* aout = (float4*)alpha + (size_t)r * N_EDGES;
    if (deg <= 64) {
      int i = s0 + lane;
      float p0 = 0.f, p1 = 0.f, p2 = 0.f, p3 = 0.f;
      if (lane < deg) {
        int s = cp[i];
        float4 els = ((const float4*)el)[(size_t)r * N_NODES + s];
        float e0 = els.x + ern.x; e0 = e0 > 0.f ? e0 : NEG_SLOPE * e0; p0 = __expf(e0);
        float e1 = els.y + ern.y; e1 = e1 > 0.f ? e1 : NEG_SLOPE * e1; p1 = __expf(e1);
        float e2 = els.z + ern.z; e2 = e2 > 0.f ? e2 : NEG_SLOPE * e2; p2 = __expf(e2);
        float e3 = els.w + ern.w; e3 = e3 > 0.f ? e3 : NEG_SLOPE * e3; p3 = __expf(e3);
      }
      float d0 = p0, d1 = p1, d2 = p2, d3 = p3;
#pragma unroll
      for (int o = 1; o < 64; o <<= 1) {
        d0 += __shfl_xor(d0, o); d1 += __shfl_xor(d1, o);
        d2 += __shfl_xor(d2, o); d3 += __shfl_xor(d3, o);
      }
      float i0 = 1.f / fmaxf(d0, 1e-30f), i1 = 1.f / fmaxf(d1, 1e-30f);
      float i2 = 1.f / fmaxf(d2, 1e-30f), i3 = 1.f / fmaxf(d3, 1e-30f);
      if (lane < deg) aout[i] = make_float4(p0 * i0, p1 * i1, p2 * i2, p3 * i3);
    } else {
      float d0 = 0.f, d1 = 0.f, d2 = 0.f, d3 = 0.f;
      for (int base = s0; base < s1; base += 64) {
        int i = base + lane;
        float p0 = 0.f, p1 = 0.f, p2 = 0.f, p3 = 0.f;
        if (i < s1) {
          int s = cp[i];
          float4 els = ((const float4*)el)[(size_t)r * N_NODES + s];
          float e0 = els.x + ern.x; e0 = e0 > 0.f ? e0 : NEG_SLOPE * e0; p0 = __expf(e0);
          float e1 = els.y + ern.y; e1 = e1 > 0.f ? e1 : NEG_SLOPE * e1; p1 = __expf(e1);
          float e2 = els.z + ern.z; e2 = e2 > 0.f ? e2 : NEG_SLOPE * e2; p2 = __expf(e2);
          float e3 = els.w + ern.w; e3 = e3 > 0.f ? e3 : NEG_SLOPE * e3; p3 = __expf(e3);
          aout[i] = make_float4(p0, p1, p2, p3);
        }
        float c0 = p0, c1 = p1, c2 = p2, c3 = p3;
#pragma unroll
        for (int o = 1; o < 64; o <<= 1) {
          c0 += __shfl_xor(c0, o); c1 += __shfl_xor(c1, o);
          c2 += __shfl_xor(c2, o); c3 += __shfl_xor(c3, o);
        }
        d0 += c0; d1 += c1; d2 += c2; d3 += c3;
      }
      float i0 = 1.f / fmaxf(d0, 1e-30f), i1 = 1.f / fmaxf(d1, 1e-30f);
      float i2 = 1.f / fmaxf(d2, 1e-30f), i3 = 1.f / fmaxf(d3, 1e-30f);
      for (int base = s0; base < s1; base += 64) {
        int i = base + lane;
        if (i < s1) {
          float4 v = aout[i];
          aout[i] = make_float4(v.x * i0, v.y * i1, v.z * i2, v.w * i3);
        }
      }
    }
  }
}

// ---------------- aggregation: pure weighted gather-sum ----------------

__global__ void agg_kernel(const unsigned short* __restrict__ featb,
                           const float* __restrict__ alpha,
                           const int* __restrict__ row_ptr, const int* __restrict__ col,
                           const float* __restrict__ bias,
                           unsigned short* __restrict__ hH, unsigned short* __restrict__ hL,
                           float* __restrict__ outF, int final_layer) {
  int n = blockIdx.x * 4 + (threadIdx.x >> 6);
  int L = threadIdx.x & 63;
  if (n >= N_NODES) return;
  const int hsel = L >> 4;
  const float third = 1.0f / 3.0f;
  float os0 = 0.f, os1 = 0.f, os2 = 0.f, os3 = 0.f;
#pragma unroll
  for (int r = 0; r < N_REL; r++) {
    int s0 = row_ptr[r * RP_STRIDE + n], s1 = row_ptr[r * RP_STRIDE + n + 1];
    const int* cp = col + (size_t)r * N_EDGES;
    const float* ap = alpha + (size_t)r * N_EDGES * 4;
    const unsigned short* fbase = featb + r * 256 + 4 * L;
    float a0 = 0.f, a1 = 0.f, a2 = 0.f, a3 = 0.f;
    int i = s0;
    for (; i + 1 < s1; i += 2) {
      int sA = cp[i], sB = cp[i + 1];
      float wA = ap[(size_t)i * 4 + hsel];
      float wB = ap[(size_t)(i + 1) * 4 + hsel];
      ushort4 fA = *(const ushort4*)&fbase[(size_t)sA * 768];
      ushort4 fB = *(const ushort4*)&fbase[(size_t)sB * 768];
      a0 += wA * bf2f(fA.x) + wB * bf2f(fB.x);
      a1 += wA * bf2f(fA.y) + wB * bf2f(fB.y);
      a2 += wA * bf2f(fA.z) + wB * bf2f(fB.z);
      a3 += wA * bf2f(fA.w) + wB * bf2f(fB.w);
    }
    if (i < s1) {
      int sA = cp[i];
      float wA = ap[(size_t)i * 4 + hsel];
      ushort4 fA = *(const ushort4*)&fbase[(size_t)sA * 768];
      a0 += wA * bf2f(fA.x); a1 += wA * bf2f(fA.y);
      a2 += wA * bf2f(fA.z); a3 += wA * bf2f(fA.w);
    }
    float4 bv = *(const float4*)&bias[r * 256 + 4 * L];
    float o0 = a0 + bv.x, o1 = a1 + bv.y, o2 = a2 + bv.z, o3 = a3 + bv.w;
    o0 = o0 > 0.f ? o0 : __expf(o0) - 1.0f;  // elu
    o1 = o1 > 0.f ? o1 : __expf(o1) - 1.0f;
    o2 = o2 > 0.f ? o2 : __expf(o2) - 1.0f;
    o3 = o3 > 0.f ? o3 : __expf(o3) - 1.0f;
    os0 += o0 * third; os1 += o1 * third; os2 += o2 * third; os3 += o3 * third;
  }
  if (final_layer) {
#pragma unroll
    for (int o = 16; o <= 32; o <<= 1) {
      os0 += __shfl_xor(os0, o); os1 += __shfl_xor(os1, o);
      os2 += __shfl_xor(os2, o); os3 += __shfl_xor(os3, o);
    }
    if (L < 16)
      *(float4*)&outF[(size_t)n * 64 + L * 4] =
          make_float4(0.25f * os0, 0.25f * os1, 0.25f * os2, 0.25f * os3);
  } else {
    ushort4 h, l;
    h.x = f2bf(os0); l.x = f2bf(os0 - bf2f(h.x));
    h.y = f2bf(os1); l.y = f2bf(os1 - bf2f(h.y));
    h.z = f2bf(os2); l.z = f2bf(os2 - bf2f(h.z));
    h.w = f2bf(os3); l.w = f2bf(os3 - bf2f(h.w));
    *(ushort4*)&hH[(size_t)n * 256 + 4 * L] = h;
    *(ushort4*)&hL[(size_t)n * 256 + 4 * L] = l;
  }
}

// ---------------- launch ----------------

extern "C" void kernel_launch(void* const* d_in, const int* in_sizes, int n_in,
                              void* d_out, int out_size, void* d_ws, size_t ws_size,
                              hipStream_t stream) {
  (void)in_sizes; (void)n_in; (void)out_size; (void)ws_size;
  const float* x = (const float*)d_in[0];
  const int* src = (const int*)d_in[1];
  const int* dst = (const int*)d_in[2];
  const float* Wl[3]  = {(const float*)d_in[3], (const float*)d_in[7], (const float*)d_in[11]};
  const float* alL[3] = {(const float*)d_in[4], (const float*)d_in[8], (const float*)d_in[12]};
  const float* arL[3] = {(const float*)d_in[5], (const float*)d_in[9], (const float*)d_in[13]};
  const float* bL[3]  = {(const float*)d_in[6], (const float*)d_in[10], (const float*)d_in[14]};

  char* p = (char*)d_ws;
  auto alloc = [&](size_t bytes) {
    char* q = p;
    p += (bytes + 255) & ~size_t(255);
    return q;
  };
  unsigned short* hH = (unsigned short*)alloc((size_t)N_NODES * 256 * 2);
  unsigned short* hL = (unsigned short*)alloc((size_t)N_NODES * 256 * 2);
  unsigned short* featb = (unsigned short*)alloc((size_t)N_NODES * 768 * 2);
  float* el      = (float*)alloc((size_t)N_REL * N_NODES * 4 * 4);
  float* er      = (float*)alloc((size_t)N_REL * N_NODES * 4 * 4);
  float* alphaw  = (float*)alloc((size_t)N_REL * N_EDGES * 4 * 4);
  int*   cnt     = (int*)alloc((size_t)N_REL * N_NODES * 4);
  int*   cursor  = (int*)alloc((size_t)N_REL * N_NODES * 4);
  int*   row_ptr = (int*)alloc((size_t)N_REL * RP_STRIDE * 4 + 64);
  int*   col     = (int*)alloc((size_t)N_REL * N_EDGES * 4);
  int*   psum    = (int*)alloc((size_t)N_REL * SCAN_BLOCKS * 4);
  unsigned short* Whi = (unsigned short*)alloc((size_t)9 * 65536 * 2);
  unsigned short* Wlo = (unsigned short*)alloc((size_t)9 * 65536 * 2);

  hipMemsetAsync(cnt, 0, (size_t)N_REL * N_NODES * 4, stream);
  const int totalE = N_REL * N_EDGES;
  count_kernel<<<(totalE + 255) / 256, 256, 0, stream>>>(dst, cnt, totalE);
  block_reduce_kernel<<<N_REL * SCAN_BLOCKS, 256, 0, stream>>>(cnt, psum);
  psum_scan_kernel<<<N_REL, 64, 0, stream>>>(psum, row_ptr);
  scan_write_kernel<<<N_REL * SCAN_BLOCKS, 256, 0, stream>>>(cnt, psum, row_ptr, cursor);
  scatter_kernel<<<(totalE + 255) / 256, 256, 0, stream>>>(src, dst, cursor, col, totalE);
  wsplit_kernel<<<9 * 64, 256, 0, stream>>>(Wl[0], Wl[1], Wl[2], Whi, Wlo);

  const int nodeBlocks = (N_NODES + 3) / 4;
  for (int l = 0; l < 3; l++) {
    gemm_mfma_kernel<<<dim3(6, (N_NODES + 127) / 128), 256, 0, stream>>>(
        x, hH, hL, Whi + (size_t)l * 3 * 65536, Wlo + (size_t)l * 3 * 65536,
        alL[l], arL[l], featb, el, er, N_NODES, l == 0);
    alpha_kernel<<<nodeBlocks, 256, 0, stream>>>(el, er, row_ptr, col, alphaw);
    agg_kernel<<<nodeBlocks, 256, 0, stream>>>(
        featb, alphaw, row_ptr, col, bL[l], hH, hL, (float*)d_out, l == 2);
  }
}